// Round 4
// baseline (385.198 us; speedup 1.0000x reference)
//
#include <hip/hip_runtime.h>

// GAT forward, MI355X. Round 3: attn occupancy (1 i-tile/wave, j-split for
// layer-1) + bitpacked adjacency.
// B=8, N=1024, F=256, O=128, H=8, HO=1024, BH=64.
//
// Pipeline:
//   pack_adj      : adj int32 [B,N,N] -> 1 bit/entry [B*N][16] ull (ballot)
//   transpose_cvt : W_att -> bf16 [H,O,F]; W_out -> bf16 [O,HO]
//   cvt_bf16      : lin_w, ln_w -> bf16
//   gemmT  (x2)   : h^T = (act @ W)^T bf16, fused s1/s2 dots (MFMA 16x16x32)
//   attn_mfma(x2) : single-pass softmax (bounded logits) + MFMA PV.
//                   jsplit=1: wave = 16 i x full j (layer-0, 1024 blocks)
//                   jsplit=4: 4 waves share 16 i, 256 j each, LDS reduce
//                   (layer-1, 512 blocks)
//   final_mfma    : y = x@lin_w.T+lin_b+out2; out = relu(y@ln_w.T+ln_b)
//
// ws floats:
//   out2 [8192,128] @ 0        (1,048,576)
//   s1 @ 1048576  s2 @ 1114112 (65,536 each)
//   s1o @ 1179648 s2o @ 1187840 (8,192 each)
// ushort region @ float offset 1196032:
//   x_b     [8,1024,1024] @ 0         h_catTb @ 8388608   h2Tb @ 16777216
//   W_attTb @ 17825792    W_outTb @ 18087936
//   lin_wb  @ 18219008    ln_wb   @ 18350080
//   adjp (ull[8192*16]) @ ushort 18366464  (1 MB, 8B-aligned)

#define NN 1024
#define FF 256
#define OO 128
#define HH 8
#define HO 1024

typedef __attribute__((ext_vector_type(8))) short short8;
typedef __attribute__((ext_vector_type(4))) float floatx4;

__device__ __forceinline__ ushort f2b(float f) {
    union { float f; unsigned u; } v; v.f = f;
    unsigned r = v.u + 0x7FFFu + ((v.u >> 16) & 1u);   // RNE
    return (ushort)(r >> 16);
}
__device__ __forceinline__ float b2f(ushort u) {
    union { unsigned u; float f; } v; v.u = ((unsigned)u) << 16;
    return v.f;
}

// ---------------- adj int32 -> bitmask (1 row per wave iter chunk) ----------
__global__ __launch_bounds__(256) void pack_adj(
    const int* __restrict__ adj, unsigned long long* __restrict__ adjp)
{
    int w = blockIdx.x * 4 + (threadIdx.x >> 6);   // row 0..8191 (= b*N+i)
    int lane = threadIdx.x & 63;
    const int* row = adj + (long)w * NN;
#pragma unroll
    for (int it = 0; it < 16; it++) {
        unsigned long long m = __ballot(row[it * 64 + lane] > 0);
        if (lane == 0) adjp[(long)w * 16 + it] = m;
    }
}

// ---------------- transpose + bf16 cvt: dst[z][c][r] = src[z][r][c] ----------
__global__ __launch_bounds__(256) void transpose_cvt(
    const float* __restrict__ src, ushort* __restrict__ dst, int R, int C)
{
    __shared__ float tile[64][65];
    int r0 = blockIdx.x * 64, c0 = blockIdx.y * 64;
    src += (long)blockIdx.z * R * C;
    dst += (long)blockIdx.z * R * C;
    int t = threadIdx.x;
    int lr = t >> 4, lc = (t & 15) * 4;
#pragma unroll
    for (int p = 0; p < 4; p++) {
        float4 v = *(const float4*)(src + (long)(r0 + p * 16 + lr) * C + c0 + lc);
        tile[p * 16 + lr][lc] = v.x; tile[p * 16 + lr][lc + 1] = v.y;
        tile[p * 16 + lr][lc + 2] = v.z; tile[p * 16 + lr][lc + 3] = v.w;
    }
    __syncthreads();
    int c = t >> 2, rq = (t & 3) * 16;
    union { ushort s[16]; uint4 q[2]; } u;
#pragma unroll
    for (int k = 0; k < 16; k++) u.s[k] = f2b(tile[rq + k][c]);
    uint4* dp = (uint4*)(dst + (long)(c0 + c) * R + r0 + rq);
    dp[0] = u.q[0]; dp[1] = u.q[1];
}

// ---------------- elementwise fp32 -> bf16 (8 el/thread) --------------------
__global__ __launch_bounds__(256) void cvt_bf16(
    const float* __restrict__ src, ushort* __restrict__ dst)
{
    long i = ((long)blockIdx.x * 256 + threadIdx.x) * 8;
    float4 v0 = *(const float4*)(src + i);
    float4 v1 = *(const float4*)(src + i + 4);
    union { ushort s[8]; uint4 q; } u;
    u.s[0] = f2b(v0.x); u.s[1] = f2b(v0.y); u.s[2] = f2b(v0.z); u.s[3] = f2b(v0.w);
    u.s[4] = f2b(v1.x); u.s[5] = f2b(v1.y); u.s[6] = f2b(v1.z); u.s[7] = f2b(v1.w);
    *(uint4*)(dst + i) = u.q;
}

// ---------------- bf16 MFMA "NT" GEMM with transposed output + fused dots ---
__global__ __launch_bounds__(256) void gemmT(
    const ushort* __restrict__ AT, const float* __restrict__ Bf,
    const ushort* __restrict__ Bb,
    ushort* __restrict__ Cb, float* __restrict__ s1, float* __restrict__ s2,
    const float* __restrict__ a1g, const float* __restrict__ a2g,
    int K, int Hh, int bBf)
{
    int t = threadIdx.x;
    int wave = t >> 6, lane = t & 63;
    int quad = lane >> 4, l16 = lane & 15;
    int bh = blockIdx.y;
    int hh = bh % Hh, b = bh / Hh;
    int n0w = blockIdx.x * 64 + wave * 16;

    const ushort* A = AT + (long)hh * OO * K;
    const float* browf = Bf + ((long)b * NN + n0w + l16) * K;
    const ushort* browb = Bb + ((long)b * NN + n0w + l16) * K;

    floatx4 acc[8];
    floatx4 zero = {0.f, 0.f, 0.f, 0.f};
#pragma unroll
    for (int mt = 0; mt < 8; mt++) acc[mt] = zero;

    for (int k0 = 0; k0 < K; k0 += 32) {
        int kb = k0 + quad * 8;
        short8 bfr;
        if (bBf) {
            bfr = *(const short8*)(browb + kb);
        } else {
            float4 b0 = *(const float4*)(browf + kb);
            float4 b1 = *(const float4*)(browf + kb + 4);
            bfr[0] = (short)f2b(b0.x); bfr[1] = (short)f2b(b0.y);
            bfr[2] = (short)f2b(b0.z); bfr[3] = (short)f2b(b0.w);
            bfr[4] = (short)f2b(b1.x); bfr[5] = (short)f2b(b1.y);
            bfr[6] = (short)f2b(b1.z); bfr[7] = (short)f2b(b1.w);
        }
#pragma unroll
        for (int mt = 0; mt < 8; mt++) {
            short8 af = *(const short8*)(A + (long)(mt * 16 + l16) * K + kb);
            acc[mt] = __builtin_amdgcn_mfma_f32_16x16x32_bf16(af, bfr, acc[mt], 0, 0, 0);
        }
    }

    const float* a1 = a1g + hh * OO;
    const float* a2 = a2g + hh * OO;
    float sp1 = 0.f, sp2 = 0.f;
#pragma unroll
    for (int mt = 0; mt < 8; mt++) {
        float4 v1 = *(const float4*)(a1 + mt * 16 + quad * 4);
        float4 v2 = *(const float4*)(a2 + mt * 16 + quad * 4);
        sp1 += acc[mt][0] * v1.x + acc[mt][1] * v1.y + acc[mt][2] * v1.z + acc[mt][3] * v1.w;
        sp2 += acc[mt][0] * v2.x + acc[mt][1] * v2.y + acc[mt][2] * v2.z + acc[mt][3] * v2.w;
    }
    sp1 += __shfl_xor(sp1, 16); sp1 += __shfl_xor(sp1, 32);
    sp2 += __shfl_xor(sp2, 16); sp2 += __shfl_xor(sp2, 32);
    if (lane < 16) {
        s1[(long)bh * NN + n0w + l16] = sp1;
        s2[(long)bh * NN + n0w + l16] = sp2;
    }

    ushort* cb = Cb + (long)bh * OO * NN;
#pragma unroll
    for (int mt = 0; mt < 8; mt++) {
#pragma unroll
        for (int reg = 0; reg < 4; reg++) {
            int o = mt * 16 + quad * 4 + reg;
            cb[(long)o * NN + n0w + l16] = f2b(acc[mt][reg]);
        }
    }
}

// ---------------- single-pass masked-softmax attention + MFMA PV ------------
// e^(i,j) = adjbit ? exp(lrelu(s1_i+s2_j)) : 0.
// jsplit=1: wave owns a 16-i tile, full j. jsplit=4: 4 waves share the
// block's 16-i tile, 256 j each, LDS partial reduce.
// dyn LDS: s2s[1024] | red[4][16][132] | Lred[4*16] (red/Lred only jsplit=4)
__global__ __launch_bounds__(256) void attn_mfma(
    const float* __restrict__ s1g, const float* __restrict__ s2g,
    const ushort* __restrict__ hTb, const uint* __restrict__ adjp,
    float* __restrict__ outf, ushort* __restrict__ outb,
    int Hh, int outStride, int doElu, int writeBf, int jsplit)
{
    extern __shared__ float smem_f[];
    float* s2s = smem_f;
    float* red = smem_f + NN;
    float* Lred = red + 4 * 16 * 132;

    int t = threadIdx.x;
    int wave = t >> 6, lane = t & 63;
    int quad = lane >> 4, l16 = lane & 15;
    int bh = blockIdx.y;
    int hh = bh % Hh, b = bh / Hh;
    int i0, j_lo, j_hi;
    if (jsplit == 1) {
        i0 = blockIdx.x * 64 + wave * 16;
        j_lo = 0; j_hi = NN;
    } else {
        i0 = blockIdx.x * 16;
        j_lo = wave * (NN / 4); j_hi = j_lo + NN / 4;
    }

    const float* s2r = s2g + (long)bh * NN;
    for (int j = t; j < NN; j += 256) s2s[j] = s2r[j];
    __syncthreads();

    float s1a = s1g[(long)bh * NN + i0 + l16];
    const uint* abits = adjp + ((long)b * NN + i0 + l16) * 32;
    const ushort* hT = hTb + (long)bh * OO * NN;

    floatx4 acc[8];
    floatx4 zero = {0.f, 0.f, 0.f, 0.f};
#pragma unroll
    for (int ot = 0; ot < 8; ot++) acc[ot] = zero;
    float Lp = 0.f;

    for (int j0 = j_lo; j0 < j_hi; j0 += 32) {
        uint bits = abits[j0 >> 5];
        uint mybits = (bits >> (quad * 8)) & 0xffu;
        int kb = j0 + quad * 8;
        float4 sA = *(const float4*)(s2s + kb);
        float4 sB = *(const float4*)(s2s + kb + 4);
        float se[8] = {sA.x, sA.y, sA.z, sA.w, sB.x, sB.y, sB.z, sB.w};
        short8 af;
#pragma unroll
        for (int e = 0; e < 8; e++) {
            float ea = s1a + se[e]; ea = fmaxf(ea, 0.2f * ea);
            float w = ((mybits >> e) & 1u) ? __expf(ea) : 0.f;
            ushort uw = f2b(w);
            af[e] = (short)uw;
            Lp += b2f(uw);
        }
#pragma unroll
        for (int ot = 0; ot < 8; ot++) {
            short8 bf = *(const short8*)(hT + (long)(ot * 16 + l16) * NN + kb);
            acc[ot] = __builtin_amdgcn_mfma_f32_16x16x32_bf16(af, bf, acc[ot], 0, 0, 0);
        }
    }

    Lp += __shfl_xor(Lp, 16); Lp += __shfl_xor(Lp, 32);

    if (jsplit == 1) {
        float rinv = 1.0f / Lp;
#pragma unroll
        for (int reg = 0; reg < 4; reg++) {
            float linv = __shfl(rinv, quad * 4 + reg);
            int row = i0 + quad * 4 + reg;
            if (writeBf) {
                ushort* orow = outb + (long)b * NN * outStride + hh * OO +
                               (long)row * outStride + l16;
#pragma unroll
                for (int ot = 0; ot < 8; ot++) {
                    float v = acc[ot][reg] * linv;
                    if (doElu) v = (v > 0.f) ? v : (__expf(v) - 1.0f);
                    orow[ot * 16] = f2b(v);
                }
            } else {
                float* orow = outf + (long)b * NN * outStride + hh * OO +
                              (long)row * outStride + l16;
#pragma unroll
                for (int ot = 0; ot < 8; ot++) {
                    float v = acc[ot][reg] * linv;
                    if (doElu) v = (v > 0.f) ? v : (__expf(v) - 1.0f);
                    orow[ot * 16] = v;
                }
            }
        }
    } else {
        // store partials: row-in-tile = quad*4+reg, col = ot*16+l16
#pragma unroll
        for (int ot = 0; ot < 8; ot++)
#pragma unroll
            for (int reg = 0; reg < 4; reg++)
                red[(wave * 16 + quad * 4 + reg) * 132 + ot * 16 + l16] =
                    acc[ot][reg];
        if (lane < 16) Lred[wave * 16 + l16] = Lp;
        __syncthreads();
        int row = t >> 4, c0 = (t & 15) * 8;
        float L = Lred[row] + Lred[16 + row] + Lred[32 + row] + Lred[48 + row];
        float rinv = 1.0f / L;
        int grow = i0 + row;
        float vv[8];
#pragma unroll
        for (int k = 0; k < 8; k++) {
            float s = red[row * 132 + c0 + k] + red[(16 + row) * 132 + c0 + k] +
                      red[(32 + row) * 132 + c0 + k] + red[(48 + row) * 132 + c0 + k];
            float v = s * rinv;
            if (doElu) v = (v > 0.f) ? v : (__expf(v) - 1.0f);
            vv[k] = v;
        }
        if (writeBf) {
            ushort* orow = outb + (long)b * NN * outStride + hh * OO +
                           (long)grow * outStride + c0;
#pragma unroll
            for (int k = 0; k < 8; k++) orow[k] = f2b(vv[k]);
        } else {
            float* orow = outf + (long)b * NN * outStride + hh * OO +
                          (long)grow * outStride + c0;
            *(float4*)orow = make_float4(vv[0], vv[1], vv[2], vv[3]);
            *(float4*)(orow + 4) = make_float4(vv[4], vv[5], vv[6], vv[7]);
        }
    }
}

// ---------------- final: y = x@lin_w.T+lin_b+out2; out = relu(y@ln_w.T+ln_b)
__global__ __launch_bounds__(256) void final_mfma(
    const ushort* __restrict__ xb, const float* __restrict__ out2,
    const ushort* __restrict__ lwb, const float* __restrict__ lin_b,
    const ushort* __restrict__ nwb, const float* __restrict__ ln_b,
    float* __restrict__ out)
{
    __shared__ ushort ys[32][136];
    int t = threadIdx.x;
    int wave = t >> 6, lane = t & 63;
    int quad = lane >> 4, l16 = lane & 15;
    long row0 = (long)blockIdx.x * 32;
    int n0 = wave * 32;

    floatx4 zero = {0.f, 0.f, 0.f, 0.f};
    floatx4 acc[2][2];
#pragma unroll
    for (int mt = 0; mt < 2; mt++)
#pragma unroll
        for (int nt = 0; nt < 2; nt++) acc[mt][nt] = zero;

    for (int k0 = 0; k0 < HO; k0 += 32) {
        int kb = k0 + quad * 8;
        short8 a0 = *(const short8*)(xb + (row0 + l16) * HO + kb);
        short8 a1 = *(const short8*)(xb + (row0 + 16 + l16) * HO + kb);
        short8 b0 = *(const short8*)(lwb + (long)(n0 + l16) * HO + kb);
        short8 b1 = *(const short8*)(lwb + (long)(n0 + 16 + l16) * HO + kb);
        acc[0][0] = __builtin_amdgcn_mfma_f32_16x16x32_bf16(a0, b0, acc[0][0], 0, 0, 0);
        acc[0][1] = __builtin_amdgcn_mfma_f32_16x16x32_bf16(a0, b1, acc[0][1], 0, 0, 0);
        acc[1][0] = __builtin_amdgcn_mfma_f32_16x16x32_bf16(a1, b0, acc[1][0], 0, 0, 0);
        acc[1][1] = __builtin_amdgcn_mfma_f32_16x16x32_bf16(a1, b1, acc[1][1], 0, 0, 0);
    }

#pragma unroll
    for (int nt = 0; nt < 2; nt++) {
        int col = n0 + nt * 16 + l16;
        float lb = lin_b[col];
#pragma unroll
        for (int mt = 0; mt < 2; mt++) {
#pragma unroll
            for (int reg = 0; reg < 4; reg++) {
                int row = mt * 16 + quad * 4 + reg;
                float v = acc[mt][nt][reg] + lb + out2[(row0 + row) * OO + col];
                ys[row][col] = f2b(v);
            }
        }
    }
    __syncthreads();

    floatx4 acc2[2][2];
#pragma unroll
    for (int mt = 0; mt < 2; mt++)
#pragma unroll
        for (int nt = 0; nt < 2; nt++) acc2[mt][nt] = zero;

#pragma unroll
    for (int k0 = 0; k0 < OO; k0 += 32) {
        int kb = k0 + quad * 8;
        short8 a0 = *(const short8*)&ys[l16][kb];
        short8 a1 = *(const short8*)&ys[16 + l16][kb];
        short8 b0 = *(const short8*)(nwb + (long)(n0 + l16) * OO + kb);
        short8 b1 = *(const short8*)(nwb + (long)(n0 + 16 + l16) * OO + kb);
        acc2[0][0] = __builtin_amdgcn_mfma_f32_16x16x32_bf16(a0, b0, acc2[0][0], 0, 0, 0);
        acc2[0][1] = __builtin_amdgcn_mfma_f32_16x16x32_bf16(a0, b1, acc2[0][1], 0, 0, 0);
        acc2[1][0] = __builtin_amdgcn_mfma_f32_16x16x32_bf16(a1, b0, acc2[1][0], 0, 0, 0);
        acc2[1][1] = __builtin_amdgcn_mfma_f32_16x16x32_bf16(a1, b1, acc2[1][1], 0, 0, 0);
    }

#pragma unroll
    for (int nt = 0; nt < 2; nt++) {
        int col = n0 + nt * 16 + l16;
        float nb = ln_b[col];
#pragma unroll
        for (int mt = 0; mt < 2; mt++) {
#pragma unroll
            for (int reg = 0; reg < 4; reg++) {
                int row = mt * 16 + quad * 4 + reg;
                out[(row0 + row) * OO + col] = fmaxf(acc2[mt][nt][reg] + nb, 0.f);
            }
        }
    }
}

extern "C" void kernel_launch(void* const* d_in, const int* in_sizes, int n_in,
                              void* d_out, int out_size, void* d_ws, size_t ws_size,
                              hipStream_t stream)
{
    const float* inputs = (const float*)d_in[0];
    const int*   adj    = (const int*)d_in[1];
    const float* W_att  = (const float*)d_in[3];
    const float* a_src  = (const float*)d_in[4];
    const float* a_dst  = (const float*)d_in[5];
    const float* W_out  = (const float*)d_in[6];
    const float* ao_src = (const float*)d_in[7];
    const float* ao_dst = (const float*)d_in[8];
    const float* lin_w  = (const float*)d_in[9];
    const float* lin_b  = (const float*)d_in[10];
    const float* ln_w   = (const float*)d_in[11];
    const float* ln_b   = (const float*)d_in[12];
    float* out = (float*)d_out;

    float* ws   = (float*)d_ws;
    float* out2 = ws;
    float* s1   = ws + 1048576;
    float* s2   = ws + 1114112;
    float* s1o  = ws + 1179648;
    float* s2o  = ws + 1187840;
    ushort* ub      = (ushort*)(ws + 1196032);
    ushort* x_b     = ub;
    ushort* h_catTb = ub + 8388608;
    ushort* h2Tb    = ub + 16777216;
    ushort* W_attTb = ub + 17825792;
    ushort* W_outTb = ub + 18087936;
    ushort* lin_wb  = ub + 18219008;
    ushort* ln_wb   = ub + 18350080;
    unsigned long long* adjp = (unsigned long long*)(ub + 18366464);

    const int SH1 = NN * 4;                              // 4096 B
    const int SH4 = (NN + 4 * 16 * 132 + 64) * 4;        // 38144 B

    // 0. packing / conversions
    pack_adj<<<2048, 256, 0, stream>>>(adj, adjp);
    transpose_cvt<<<dim3(4, 2, 8), 256, 0, stream>>>(W_att, W_attTb, FF, OO);
    transpose_cvt<<<dim3(16, 2, 1), 256, 0, stream>>>(W_out, W_outTb, HO, OO);
    cvt_bf16<<<64, 256, 0, stream>>>(lin_w, lin_wb);
    cvt_bf16<<<8, 256, 0, stream>>>(ln_w, ln_wb);
    // 1. h^T = (inputs @ W_att)^T per (b,h), bf16; fused s1/s2
    gemmT<<<dim3(16, 64), 256, 0, stream>>>(
        W_attTb, inputs, (const ushort*)nullptr, h_catTb, s1, s2,
        a_src, a_dst, FF, HH, 0);
    // 2. layer-0 attention -> x = elu(att@h) bf16
    attn_mfma<<<dim3(16, 64), 256, SH1, stream>>>(
        s1, s2, h_catTb, (const uint*)adjp, (float*)nullptr, x_b,
        HH, HO, 1, 1, 1);
    // 3. h2^T = (x @ W_out)^T per b, bf16; fused s1o/s2o
    gemmT<<<dim3(16, 8), 256, 0, stream>>>(
        W_outTb, (const float*)nullptr, x_b, h2Tb, s1o, s2o,
        ao_src, ao_dst, HO, 1, 1);
    // 4. layer-1 attention -> out2 fp32 (no elu), j-split x4
    attn_mfma<<<dim3(64, 8), 256, SH4, stream>>>(
        s1o, s2o, h2Tb, (const uint*)adjp, out2, (ushort*)nullptr,
        1, OO, 0, 0, 4);
    // 5. out = relu((x@lin_w.T + lin_b + out2) @ ln_w.T + ln_b)
    final_mfma<<<256, 256, 0, stream>>>(
        x_b, out2, lin_wb, lin_b, ln_wb, ln_b, out);
}

// Round 5
// 288.626 us; speedup vs baseline: 1.3346x; 1.3346x over previous
//
#include <hip/hip_runtime.h>

// GAT forward, MI355X. Round 4: attn = 32 i/wave + block j-split x2 + packed
// h^T fragment layout + load-then-exp-then-MFMA ordering.
// B=8, N=1024, F=256, O=128, H=8, HO=1024, BH=64.
//
// h^T packed layout per (b,h): hTp[chunk][o][d]  (chunk=j>>3, d=j&7)
//   elem (j,o) at chunk*1024 + o*8 + d. MFMA B-frag (ot,j0,quad,l16) =
//   short8 @ ((j0>>3)+quad)*1024 + ot*128 + l16*8  -> 4x256B segments/wave.
//
// ws floats:
//   out2 [8192,128] @ 0        (1,048,576)
//   s1 @ 1048576  s2 @ 1114112 (65,536 each)
//   s1o @ 1179648 s2o @ 1187840 (8,192 each)
// ushort region @ float offset 1196032:
//   x_b     [8,1024,1024] @ 0         h_catTb @ 8388608   h2Tb @ 16777216
//   W_attTb @ 17825792    W_outTb @ 18087936
//   lin_wb  @ 18219008    ln_wb   @ 18350080
//   adjp (ull[8192*16]) @ ushort 18366464  (1 MB)

#define NN 1024
#define FF 256
#define OO 128
#define HH 8
#define HO 1024

typedef __attribute__((ext_vector_type(8))) short short8;
typedef __attribute__((ext_vector_type(4))) float floatx4;

__device__ __forceinline__ ushort f2b(float f) {
    union { float f; unsigned u; } v; v.f = f;
    unsigned r = v.u + 0x7FFFu + ((v.u >> 16) & 1u);   // RNE
    return (ushort)(r >> 16);
}

// ---------------- adj int32 -> bitmask ----------
__global__ __launch_bounds__(256) void pack_adj(
    const int* __restrict__ adj, unsigned long long* __restrict__ adjp)
{
    int w = blockIdx.x * 4 + (threadIdx.x >> 6);   // row 0..8191 (= b*N+i)
    int lane = threadIdx.x & 63;
    const int* row = adj + (long)w * NN;
#pragma unroll
    for (int it = 0; it < 16; it++) {
        unsigned long long m = __ballot(row[it * 64 + lane] > 0);
        if (lane == 0) adjp[(long)w * 16 + it] = m;
    }
}

// ---------------- transpose + bf16 cvt: dst[z][c][r] = src[z][r][c] ----------
__global__ __launch_bounds__(256) void transpose_cvt(
    const float* __restrict__ src, ushort* __restrict__ dst, int R, int C)
{
    __shared__ float tile[64][65];
    int r0 = blockIdx.x * 64, c0 = blockIdx.y * 64;
    src += (long)blockIdx.z * R * C;
    dst += (long)blockIdx.z * R * C;
    int t = threadIdx.x;
    int lr = t >> 4, lc = (t & 15) * 4;
#pragma unroll
    for (int p = 0; p < 4; p++) {
        float4 v = *(const float4*)(src + (long)(r0 + p * 16 + lr) * C + c0 + lc);
        tile[p * 16 + lr][lc] = v.x; tile[p * 16 + lr][lc + 1] = v.y;
        tile[p * 16 + lr][lc + 2] = v.z; tile[p * 16 + lr][lc + 3] = v.w;
    }
    __syncthreads();
    int c = t >> 2, rq = (t & 3) * 16;
    union { ushort s[16]; uint4 q[2]; } u;
#pragma unroll
    for (int k = 0; k < 16; k++) u.s[k] = f2b(tile[rq + k][c]);
    uint4* dp = (uint4*)(dst + (long)(c0 + c) * R + r0 + rq);
    dp[0] = u.q[0]; dp[1] = u.q[1];
}

// ---------------- elementwise fp32 -> bf16 (8 el/thread) --------------------
__global__ __launch_bounds__(256) void cvt_bf16(
    const float* __restrict__ src, ushort* __restrict__ dst)
{
    long i = ((long)blockIdx.x * 256 + threadIdx.x) * 8;
    float4 v0 = *(const float4*)(src + i);
    float4 v1 = *(const float4*)(src + i + 4);
    union { ushort s[8]; uint4 q; } u;
    u.s[0] = f2b(v0.x); u.s[1] = f2b(v0.y); u.s[2] = f2b(v0.z); u.s[3] = f2b(v0.w);
    u.s[4] = f2b(v1.x); u.s[5] = f2b(v1.y); u.s[6] = f2b(v1.z); u.s[7] = f2b(v1.w);
    *(uint4*)(dst + i) = u.q;
}

// ---------------- bf16 MFMA "NT" GEMM, packed-h^T output + fused dots -------
__global__ __launch_bounds__(256) void gemmT(
    const ushort* __restrict__ AT, const float* __restrict__ Bf,
    const ushort* __restrict__ Bb,
    ushort* __restrict__ Cb, float* __restrict__ s1, float* __restrict__ s2,
    const float* __restrict__ a1g, const float* __restrict__ a2g,
    int K, int Hh, int bBf)
{
    int t = threadIdx.x;
    int wave = t >> 6, lane = t & 63;
    int quad = lane >> 4, l16 = lane & 15;
    int bh = blockIdx.y;
    int hh = bh % Hh, b = bh / Hh;
    int n0w = blockIdx.x * 64 + wave * 16;

    const ushort* A = AT + (long)hh * OO * K;
    const float* browf = Bf + ((long)b * NN + n0w + l16) * K;
    const ushort* browb = Bb + ((long)b * NN + n0w + l16) * K;

    floatx4 acc[8];
    floatx4 zero = {0.f, 0.f, 0.f, 0.f};
#pragma unroll
    for (int mt = 0; mt < 8; mt++) acc[mt] = zero;

    for (int k0 = 0; k0 < K; k0 += 32) {
        int kb = k0 + quad * 8;
        short8 bfr;
        if (bBf) {
            bfr = *(const short8*)(browb + kb);
        } else {
            float4 b0 = *(const float4*)(browf + kb);
            float4 b1 = *(const float4*)(browf + kb + 4);
            bfr[0] = (short)f2b(b0.x); bfr[1] = (short)f2b(b0.y);
            bfr[2] = (short)f2b(b0.z); bfr[3] = (short)f2b(b0.w);
            bfr[4] = (short)f2b(b1.x); bfr[5] = (short)f2b(b1.y);
            bfr[6] = (short)f2b(b1.z); bfr[7] = (short)f2b(b1.w);
        }
#pragma unroll
        for (int mt = 0; mt < 8; mt++) {
            short8 af = *(const short8*)(A + (long)(mt * 16 + l16) * K + kb);
            acc[mt] = __builtin_amdgcn_mfma_f32_16x16x32_bf16(af, bfr, acc[mt], 0, 0, 0);
        }
    }

    const float* a1 = a1g + hh * OO;
    const float* a2 = a2g + hh * OO;
    float sp1 = 0.f, sp2 = 0.f;
#pragma unroll
    for (int mt = 0; mt < 8; mt++) {
        float4 v1 = *(const float4*)(a1 + mt * 16 + quad * 4);
        float4 v2 = *(const float4*)(a2 + mt * 16 + quad * 4);
        sp1 += acc[mt][0] * v1.x + acc[mt][1] * v1.y + acc[mt][2] * v1.z + acc[mt][3] * v1.w;
        sp2 += acc[mt][0] * v2.x + acc[mt][1] * v2.y + acc[mt][2] * v2.z + acc[mt][3] * v2.w;
    }
    sp1 += __shfl_xor(sp1, 16); sp1 += __shfl_xor(sp1, 32);
    sp2 += __shfl_xor(sp2, 16); sp2 += __shfl_xor(sp2, 32);
    if (lane < 16) {
        s1[(long)bh * NN + n0w + l16] = sp1;
        s2[(long)bh * NN + n0w + l16] = sp2;
    }

    // store h^T bf16, fragment-packed: (o,n) -> (n>>3)*1024 + o*8 + (n&7)
    ushort* cb = Cb + (long)bh * OO * NN;
    int n = n0w + l16;
    int base = (n >> 3) * 1024 + (n & 7);
#pragma unroll
    for (int mt = 0; mt < 8; mt++) {
#pragma unroll
        for (int reg = 0; reg < 4; reg++) {
            int o = mt * 16 + quad * 4 + reg;
            cb[base + o * 8] = f2b(acc[mt][reg]);
        }
    }
}

// ---------------- single-pass masked-softmax attention + MFMA PV ------------
// JS=2 (layer 0): 4 waves = 2 i-groups(32 i) x 2 j-halves(512 j); LDS reduce.
// JS=4 (layer 1): 4 waves share one 16-i tile, 256 j each; LDS reduce.
// dyn LDS: s2s[1024] | red[8448] (stride 132) | Lred[64]
template <int JS>
__global__ __launch_bounds__(256) void attn_mfma(
    const float* __restrict__ s1g, const float* __restrict__ s2g,
    const ushort* __restrict__ hTp, const uint* __restrict__ adjp,
    float* __restrict__ outf, ushort* __restrict__ outb,
    int Hh, int outStride, int doElu, int writeBf)
{
    extern __shared__ float smem_f[];
    float* s2s = smem_f;
    float* red = smem_f + NN;
    float* Lred = red + 8448;

    int t = threadIdx.x;
    int wave = t >> 6, lane = t & 63;
    int quad = lane >> 4, l16 = lane & 15;
    int bh = blockIdx.y;
    int hh = bh % Hh, b = bh / Hh;

    const float* s2r = s2g + (long)bh * NN;
    for (int j = t; j < NN; j += 256) s2s[j] = s2r[j];
    __syncthreads();

    const ushort* hT = hTp + (long)bh * OO * NN;
    floatx4 zero = {0.f, 0.f, 0.f, 0.f};

    if (JS == 2) {
        int ig = wave >> 1, jh = wave & 1;
        int i0 = blockIdx.x * 64 + ig * 32;
        int j_lo = jh * (NN / 2), j_hi = j_lo + NN / 2;

        float s1a = s1g[(long)bh * NN + i0 + l16];
        float s1b = s1g[(long)bh * NN + i0 + 16 + l16];
        const uint* abA = adjp + ((long)b * NN + i0 + l16) * 32;
        const uint* abB = abA + 16 * 32;

        floatx4 acc0[8], acc1[8];
#pragma unroll
        for (int ot = 0; ot < 8; ot++) { acc0[ot] = zero; acc1[ot] = zero; }
        float Lp0 = 0.f, Lp1 = 0.f;

        for (int j0 = j_lo; j0 < j_hi; j0 += 32) {
            // 1) issue B-fragment loads
            const ushort* hp = hT + ((j0 >> 3) + quad) * 1024 + l16 * 8;
            short8 bf[8];
#pragma unroll
            for (int ot = 0; ot < 8; ot++)
                bf[ot] = *(const short8*)(hp + ot * 128);
            // 2) e^ VALU block (covers load latency)
            uint mbA = (abA[j0 >> 5] >> (quad * 8)) & 0xffu;
            uint mbB = (abB[j0 >> 5] >> (quad * 8)) & 0xffu;
            int kb = j0 + quad * 8;
            float4 sA4 = *(const float4*)(s2s + kb);
            float4 sB4 = *(const float4*)(s2s + kb + 4);
            float se[8] = {sA4.x, sA4.y, sA4.z, sA4.w, sB4.x, sB4.y, sB4.z, sB4.w};
            short8 afA, afB;
#pragma unroll
            for (int e = 0; e < 8; e++) {
                float ea = s1a + se[e]; ea = fmaxf(ea, 0.2f * ea);
                float eb = s1b + se[e]; eb = fmaxf(eb, 0.2f * eb);
                union { float f; uint u; } wa, wb;
                wa.f = ((mbA >> e) & 1u) ? __expf(ea) : 0.f;
                wb.f = ((mbB >> e) & 1u) ? __expf(eb) : 0.f;
                wa.u &= 0xffff0000u; wb.u &= 0xffff0000u;   // truncate to bf16
                afA[e] = (short)(wa.u >> 16);
                afB[e] = (short)(wb.u >> 16);
                Lp0 += wa.f; Lp1 += wb.f;
            }
            // 3) MFMA (B shared by both i-tiles)
#pragma unroll
            for (int ot = 0; ot < 8; ot++) {
                acc0[ot] = __builtin_amdgcn_mfma_f32_16x16x32_bf16(afA, bf[ot], acc0[ot], 0, 0, 0);
                acc1[ot] = __builtin_amdgcn_mfma_f32_16x16x32_bf16(afB, bf[ot], acc1[ot], 0, 0, 0);
            }
        }

        Lp0 += __shfl_xor(Lp0, 16); Lp0 += __shfl_xor(Lp0, 32);
        Lp1 += __shfl_xor(Lp1, 16); Lp1 += __shfl_xor(Lp1, 32);

        if (jh == 1) {
#pragma unroll
            for (int ot = 0; ot < 8; ot++)
#pragma unroll
                for (int reg = 0; reg < 4; reg++) {
                    red[(ig * 32 + quad * 4 + reg) * 132 + ot * 16 + l16] = acc0[ot][reg];
                    red[(ig * 32 + 16 + quad * 4 + reg) * 132 + ot * 16 + l16] = acc1[ot][reg];
                }
            if (lane < 16) {
                Lred[(ig * 2 + 0) * 16 + l16] = Lp0;
                Lred[(ig * 2 + 1) * 16 + l16] = Lp1;
            }
        }
        __syncthreads();
        if (jh == 0) {
            float r0 = 1.0f / (Lp0 + Lred[(ig * 2 + 0) * 16 + l16]);
            float r1 = 1.0f / (Lp1 + Lred[(ig * 2 + 1) * 16 + l16]);
#pragma unroll
            for (int tile = 0; tile < 2; tile++) {
                float rv = tile ? r1 : r0;
                floatx4* ac = tile ? acc1 : acc0;
#pragma unroll
                for (int reg = 0; reg < 4; reg++) {
                    float linv = __shfl(rv, quad * 4 + reg);
                    int rloc = ig * 32 + tile * 16 + quad * 4 + reg;
                    int row = blockIdx.x * 64 + rloc;
                    if (writeBf) {
                        ushort* orow = outb + (long)b * NN * outStride + hh * OO +
                                       (long)row * outStride + l16;
#pragma unroll
                        for (int ot = 0; ot < 8; ot++) {
                            float v = (ac[ot][reg] + red[rloc * 132 + ot * 16 + l16]) * linv;
                            if (doElu) v = (v > 0.f) ? v : (__expf(v) - 1.0f);
                            orow[ot * 16] = f2b(v);
                        }
                    } else {
                        float* orow = outf + (long)b * NN * outStride + hh * OO +
                                      (long)row * outStride + l16;
#pragma unroll
                        for (int ot = 0; ot < 8; ot++) {
                            float v = (ac[ot][reg] + red[rloc * 132 + ot * 16 + l16]) * linv;
                            if (doElu) v = (v > 0.f) ? v : (__expf(v) - 1.0f);
                            orow[ot * 16] = v;
                        }
                    }
                }
            }
        }
    } else {   // JS == 4
        int i0 = blockIdx.x * 16;
        int j_lo = wave * (NN / 4), j_hi = j_lo + NN / 4;

        float s1a = s1g[(long)bh * NN + i0 + l16];
        const uint* abA = adjp + ((long)b * NN + i0 + l16) * 32;

        floatx4 acc[8];
#pragma unroll
        for (int ot = 0; ot < 8; ot++) acc[ot] = zero;
        float Lp = 0.f;

        for (int j0 = j_lo; j0 < j_hi; j0 += 32) {
            const ushort* hp = hT + ((j0 >> 3) + quad) * 1024 + l16 * 8;
            short8 bf[8];
#pragma unroll
            for (int ot = 0; ot < 8; ot++)
                bf[ot] = *(const short8*)(hp + ot * 128);
            uint mbA = (abA[j0 >> 5] >> (quad * 8)) & 0xffu;
            int kb = j0 + quad * 8;
            float4 sA4 = *(const float4*)(s2s + kb);
            float4 sB4 = *(const float4*)(s2s + kb + 4);
            float se[8] = {sA4.x, sA4.y, sA4.z, sA4.w, sB4.x, sB4.y, sB4.z, sB4.w};
            short8 afA;
#pragma unroll
            for (int e = 0; e < 8; e++) {
                float ea = s1a + se[e]; ea = fmaxf(ea, 0.2f * ea);
                union { float f; uint u; } wa;
                wa.f = ((mbA >> e) & 1u) ? __expf(ea) : 0.f;
                wa.u &= 0xffff0000u;
                afA[e] = (short)(wa.u >> 16);
                Lp += wa.f;
            }
#pragma unroll
            for (int ot = 0; ot < 8; ot++)
                acc[ot] = __builtin_amdgcn_mfma_f32_16x16x32_bf16(afA, bf[ot], acc[ot], 0, 0, 0);
        }

        Lp += __shfl_xor(Lp, 16); Lp += __shfl_xor(Lp, 32);
#pragma unroll
        for (int ot = 0; ot < 8; ot++)
#pragma unroll
            for (int reg = 0; reg < 4; reg++)
                red[(wave * 16 + quad * 4 + reg) * 132 + ot * 16 + l16] = acc[ot][reg];
        if (lane < 16) Lred[wave * 16 + l16] = Lp;
        __syncthreads();
        int row = t >> 4, c0 = (t & 15) * 8;
        float L = Lred[row] + Lred[16 + row] + Lred[32 + row] + Lred[48 + row];
        float rinv = 1.0f / L;
        int grow = i0 + row;
        float vv[8];
#pragma unroll
        for (int k = 0; k < 8; k++) {
            float s = red[row * 132 + c0 + k] + red[(16 + row) * 132 + c0 + k] +
                      red[(32 + row) * 132 + c0 + k] + red[(48 + row) * 132 + c0 + k];
            float v = s * rinv;
            if (doElu) v = (v > 0.f) ? v : (__expf(v) - 1.0f);
            vv[k] = v;
        }
        if (writeBf) {
            ushort* orow = outb + (long)b * NN * outStride + hh * OO +
                           (long)grow * outStride + c0;
#pragma unroll
            for (int k = 0; k < 8; k++) orow[k] = f2b(vv[k]);
        } else {
            float* orow = outf + (long)b * NN * outStride + hh * OO +
                          (long)grow * outStride + c0;
            *(float4*)orow = make_float4(vv[0], vv[1], vv[2], vv[3]);
            *(float4*)(orow + 4) = make_float4(vv[4], vv[5], vv[6], vv[7]);
        }
    }
}

// ---------------- final: y = x@lin_w.T+lin_b+out2; out = relu(y@ln_w.T+ln_b)
__global__ __launch_bounds__(256) void final_mfma(
    const ushort* __restrict__ xb, const float* __restrict__ out2,
    const ushort* __restrict__ lwb, const float* __restrict__ lin_b,
    const ushort* __restrict__ nwb, const float* __restrict__ ln_b,
    float* __restrict__ out)
{
    __shared__ ushort ys[32][136];
    int t = threadIdx.x;
    int wave = t >> 6, lane = t & 63;
    int quad = lane >> 4, l16 = lane & 15;
    long row0 = (long)blockIdx.x * 32;
    int n0 = wave * 32;

    floatx4 zero = {0.f, 0.f, 0.f, 0.f};
    floatx4 acc[2][2];
#pragma unroll
    for (int mt = 0; mt < 2; mt++)
#pragma unroll
        for (int nt = 0; nt < 2; nt++) acc[mt][nt] = zero;

    for (int k0 = 0; k0 < HO; k0 += 32) {
        int kb = k0 + quad * 8;
        short8 a0 = *(const short8*)(xb + (row0 + l16) * HO + kb);
        short8 a1 = *(const short8*)(xb + (row0 + 16 + l16) * HO + kb);
        short8 b0 = *(const short8*)(lwb + (long)(n0 + l16) * HO + kb);
        short8 b1 = *(const short8*)(lwb + (long)(n0 + 16 + l16) * HO + kb);
        acc[0][0] = __builtin_amdgcn_mfma_f32_16x16x32_bf16(a0, b0, acc[0][0], 0, 0, 0);
        acc[0][1] = __builtin_amdgcn_mfma_f32_16x16x32_bf16(a0, b1, acc[0][1], 0, 0, 0);
        acc[1][0] = __builtin_amdgcn_mfma_f32_16x16x32_bf16(a1, b0, acc[1][0], 0, 0, 0);
        acc[1][1] = __builtin_amdgcn_mfma_f32_16x16x32_bf16(a1, b1, acc[1][1], 0, 0, 0);
    }

#pragma unroll
    for (int nt = 0; nt < 2; nt++) {
        int col = n0 + nt * 16 + l16;
        float lb = lin_b[col];
#pragma unroll
        for (int mt = 0; mt < 2; mt++) {
#pragma unroll
            for (int reg = 0; reg < 4; reg++) {
                int row = mt * 16 + quad * 4 + reg;
                float v = acc[mt][nt][reg] + lb + out2[(row0 + row) * OO + col];
                ys[row][col] = f2b(v);
            }
        }
    }
    __syncthreads();

    floatx4 acc2[2][2];
#pragma unroll
    for (int mt = 0; mt < 2; mt++)
#pragma unroll
        for (int nt = 0; nt < 2; nt++) acc2[mt][nt] = zero;

#pragma unroll
    for (int k0 = 0; k0 < OO; k0 += 32) {
        int kb = k0 + quad * 8;
        short8 a0 = *(const short8*)&ys[l16][kb];
        short8 a1 = *(const short8*)&ys[16 + l16][kb];
        short8 b0 = *(const short8*)(nwb + (long)(n0 + l16) * OO + kb);
        short8 b1 = *(const short8*)(nwb + (long)(n0 + 16 + l16) * OO + kb);
        acc2[0][0] = __builtin_amdgcn_mfma_f32_16x16x32_bf16(a0, b0, acc2[0][0], 0, 0, 0);
        acc2[0][1] = __builtin_amdgcn_mfma_f32_16x16x32_bf16(a0, b1, acc2[0][1], 0, 0, 0);
        acc2[1][0] = __builtin_amdgcn_mfma_f32_16x16x32_bf16(a1, b0, acc2[1][0], 0, 0, 0);
        acc2[1][1] = __builtin_amdgcn_mfma_f32_16x16x32_bf16(a1, b1, acc2[1][1], 0, 0, 0);
    }

#pragma unroll
    for (int nt = 0; nt < 2; nt++) {
        int col = n0 + nt * 16 + l16;
        float nb = ln_b[col];
#pragma unroll
        for (int mt = 0; mt < 2; mt++) {
#pragma unroll
            for (int reg = 0; reg < 4; reg++) {
                int row = mt * 16 + quad * 4 + reg;
                out[(row0 + row) * OO + col] = fmaxf(acc2[mt][nt][reg] + nb, 0.f);
            }
        }
    }
}

extern "C" void kernel_launch(void* const* d_in, const int* in_sizes, int n_in,
                              void* d_out, int out_size, void* d_ws, size_t ws_size,
                              hipStream_t stream)
{
    const float* inputs = (const float*)d_in[0];
    const int*   adj    = (const int*)d_in[1];
    const float* W_att  = (const float*)d_in[3];
    const float* a_src  = (const float*)d_in[4];
    const float* a_dst  = (const float*)d_in[5];
    const float* W_out  = (const float*)d_in[6];
    const float* ao_src = (const float*)d_in[7];
    const float* ao_dst = (const float*)d_in[8];
    const float* lin_w  = (const float*)d_in[9];
    const float* lin_b  = (const float*)d_in[10];
    const float* ln_w   = (const float*)d_in[11];
    const float* ln_b   = (const float*)d_in[12];
    float* out = (float*)d_out;

    float* ws   = (float*)d_ws;
    float* out2 = ws;
    float* s1   = ws + 1048576;
    float* s2   = ws + 1114112;
    float* s1o  = ws + 1179648;
    float* s2o  = ws + 1187840;
    ushort* ub      = (ushort*)(ws + 1196032);
    ushort* x_b     = ub;
    ushort* h_catTb = ub + 8388608;
    ushort* h2Tb    = ub + 16777216;
    ushort* W_attTb = ub + 17825792;
    ushort* W_outTb = ub + 18087936;
    ushort* lin_wb  = ub + 18219008;
    ushort* ln_wb   = ub + 18350080;
    unsigned long long* adjp = (unsigned long long*)(ub + 18366464);

    const int SH = (NN + 8448 + 64) * 4;   // 38,144 B dyn LDS -> 4 blocks/CU

    // 0. packing / conversions
    pack_adj<<<2048, 256, 0, stream>>>(adj, adjp);
    transpose_cvt<<<dim3(4, 2, 8), 256, 0, stream>>>(W_att, W_attTb, FF, OO);
    transpose_cvt<<<dim3(16, 2, 1), 256, 0, stream>>>(W_out, W_outTb, HO, OO);
    cvt_bf16<<<64, 256, 0, stream>>>(lin_w, lin_wb);
    cvt_bf16<<<8, 256, 0, stream>>>(ln_w, ln_wb);
    // 1. h^T (packed) = (inputs @ W_att)^T per (b,h), bf16; fused s1/s2
    gemmT<<<dim3(16, 64), 256, 0, stream>>>(
        W_attTb, inputs, (const ushort*)nullptr, h_catTb, s1, s2,
        a_src, a_dst, FF, HH, 0);
    // 2. layer-0 attention -> x = elu(att@h) bf16
    attn_mfma<2><<<dim3(16, 64), 256, SH, stream>>>(
        s1, s2, h_catTb, (const uint*)adjp, (float*)nullptr, x_b, HH, HO, 1, 1);
    // 3. h2^T (packed) = (x @ W_out)^T per b, bf16; fused s1o/s2o
    gemmT<<<dim3(16, 8), 256, 0, stream>>>(
        W_outTb, (const float*)nullptr, x_b, h2Tb, s1o, s2o,
        ao_src, ao_dst, HO, 1, 1);
    // 4. layer-1 attention -> out2 fp32 (no elu), j-split x4
    attn_mfma<4><<<dim3(64, 8), 256, SH, stream>>>(
        s1o, s2o, h2Tb, (const uint*)adjp, out2, (ushort*)nullptr, 1, OO, 0, 0);
    // 5. out = relu((x@lin_w.T + lin_b + out2) @ ln_w.T + ln_b)
    final_mfma<<<256, 256, 0, stream>>>(
        x_b, out2, lin_wb, lin_b, ln_wb, ln_b, out);
}

// Round 6
// 260.837 us; speedup vs baseline: 1.4768x; 1.1065x over previous
//
#include <hip/hip_runtime.h>

// GAT forward, MI355X. Round 5: split-K layer-1 gemm (gemmT_sk), pack_adj
// folded into gemmT0, merged cvt launches.
// B=8, N=1024, F=256, O=128, H=8, HO=1024, BH=64.
//
// h^T packed layout per (b,h): elem (j,o) at (j>>3)*1024 + o*8 + (j&7).
//
// ws floats:
//   out2 [8192,128] @ 0        (1,048,576)
//   s1 @ 1048576  s2 @ 1114112 (65,536 each)
//   s1o @ 1179648 s2o @ 1187840 (8,192 each)
// ushort region @ float offset 1196032:
//   x_b     [8,1024,1024] @ 0         h_catTb @ 8388608   h2Tb @ 16777216
//   W_attTb @ 17825792    W_outTb @ 18087936
//   lin_wb  @ 18219008    ln_wb   @ 18350080
//   adjp (ull[8192*16]) @ ushort 18366464  (1 MB)

#define NN 1024
#define FF 256
#define OO 128
#define HH 8
#define HO 1024

typedef __attribute__((ext_vector_type(8))) short short8;
typedef __attribute__((ext_vector_type(4))) float floatx4;

__device__ __forceinline__ ushort f2b(float f) {
    union { float f; unsigned u; } v; v.f = f;
    unsigned r = v.u + 0x7FFFu + ((v.u >> 16) & 1u);   // RNE
    return (ushort)(r >> 16);
}

// ---------------- transpose + bf16 cvt: dst[z][c][r] = src[z][r][c] ----------
__global__ __launch_bounds__(256) void transpose_cvt(
    const float* __restrict__ src, ushort* __restrict__ dst, int R, int C)
{
    __shared__ float tile[64][65];
    int r0 = blockIdx.x * 64, c0 = blockIdx.y * 64;
    src += (long)blockIdx.z * R * C;
    dst += (long)blockIdx.z * R * C;
    int t = threadIdx.x;
    int lr = t >> 4, lc = (t & 15) * 4;
#pragma unroll
    for (int p = 0; p < 4; p++) {
        float4 v = *(const float4*)(src + (long)(r0 + p * 16 + lr) * C + c0 + lc);
        tile[p * 16 + lr][lc] = v.x; tile[p * 16 + lr][lc + 1] = v.y;
        tile[p * 16 + lr][lc + 2] = v.z; tile[p * 16 + lr][lc + 3] = v.w;
    }
    __syncthreads();
    int c = t >> 2, rq = (t & 3) * 16;
    union { ushort s[16]; uint4 q[2]; } u;
#pragma unroll
    for (int k = 0; k < 16; k++) u.s[k] = f2b(tile[rq + k][c]);
    uint4* dp = (uint4*)(dst + (long)(c0 + c) * R + r0 + rq);
    dp[0] = u.q[0]; dp[1] = u.q[1];
}

// ---------------- merged fp32->bf16 cvt for lin_w (131072) + ln_w (16384) ---
__global__ __launch_bounds__(256) void cvt_bf16_2(
    const float* __restrict__ s0, ushort* __restrict__ d0, long n0,
    const float* __restrict__ s1, ushort* __restrict__ d1)
{
    long i = ((long)blockIdx.x * 256 + threadIdx.x) * 8;
    const float* src; ushort* dst; long off;
    if (i < n0) { src = s0; dst = d0; off = i; }
    else        { src = s1; dst = d1; off = i - n0; }
    float4 v0 = *(const float4*)(src + off);
    float4 v1 = *(const float4*)(src + off + 4);
    union { ushort s[8]; uint4 q; } u;
    u.s[0] = f2b(v0.x); u.s[1] = f2b(v0.y); u.s[2] = f2b(v0.z); u.s[3] = f2b(v0.w);
    u.s[4] = f2b(v1.x); u.s[5] = f2b(v1.y); u.s[6] = f2b(v1.z); u.s[7] = f2b(v1.w);
    *(uint4*)(dst + off) = u.q;
}

// ---------------- layer-0: bf16 MFMA "NT" GEMM, packed-h^T out, fused dots,
// ---------------- folded adjacency bit-packing (2 rows/wave) ----------------
__global__ __launch_bounds__(256) void gemmT(
    const ushort* __restrict__ AT, const float* __restrict__ Bf,
    ushort* __restrict__ Cb, float* __restrict__ s1, float* __restrict__ s2,
    const float* __restrict__ a1g, const float* __restrict__ a2g,
    int K, int Hh, const int* __restrict__ adjg,
    unsigned long long* __restrict__ adjp)
{
    int t = threadIdx.x;
    int wave = t >> 6, lane = t & 63;
    int quad = lane >> 4, l16 = lane & 15;
    int bh = blockIdx.y;
    int hh = bh % Hh, b = bh / Hh;
    int n0w = blockIdx.x * 64 + wave * 16;

    const ushort* A = AT + (long)hh * OO * K;
    const float* browf = Bf + ((long)b * NN + n0w + l16) * K;

    floatx4 acc[8];
    floatx4 zero = {0.f, 0.f, 0.f, 0.f};
#pragma unroll
    for (int mt = 0; mt < 8; mt++) acc[mt] = zero;

    for (int k0 = 0; k0 < K; k0 += 32) {
        int kb = k0 + quad * 8;
        float4 b0 = *(const float4*)(browf + kb);
        float4 b1 = *(const float4*)(browf + kb + 4);
        short8 bfr;
        bfr[0] = (short)f2b(b0.x); bfr[1] = (short)f2b(b0.y);
        bfr[2] = (short)f2b(b0.z); bfr[3] = (short)f2b(b0.w);
        bfr[4] = (short)f2b(b1.x); bfr[5] = (short)f2b(b1.y);
        bfr[6] = (short)f2b(b1.z); bfr[7] = (short)f2b(b1.w);
#pragma unroll
        for (int mt = 0; mt < 8; mt++) {
            short8 af = *(const short8*)(A + (long)(mt * 16 + l16) * K + kb);
            acc[mt] = __builtin_amdgcn_mfma_f32_16x16x32_bf16(af, bfr, acc[mt], 0, 0, 0);
        }
    }

    const float* a1 = a1g + hh * OO;
    const float* a2 = a2g + hh * OO;
    float sp1 = 0.f, sp2 = 0.f;
#pragma unroll
    for (int mt = 0; mt < 8; mt++) {
        float4 v1 = *(const float4*)(a1 + mt * 16 + quad * 4);
        float4 v2 = *(const float4*)(a2 + mt * 16 + quad * 4);
        sp1 += acc[mt][0] * v1.x + acc[mt][1] * v1.y + acc[mt][2] * v1.z + acc[mt][3] * v1.w;
        sp2 += acc[mt][0] * v2.x + acc[mt][1] * v2.y + acc[mt][2] * v2.z + acc[mt][3] * v2.w;
    }
    sp1 += __shfl_xor(sp1, 16); sp1 += __shfl_xor(sp1, 32);
    sp2 += __shfl_xor(sp2, 16); sp2 += __shfl_xor(sp2, 32);
    if (lane < 16) {
        s1[(long)bh * NN + n0w + l16] = sp1;
        s2[(long)bh * NN + n0w + l16] = sp2;
    }

    // store h^T bf16, fragment-packed: (o,n) -> (n>>3)*1024 + o*8 + (n&7)
    ushort* cb = Cb + (long)bh * OO * NN;
    int n = n0w + l16;
    int base = (n >> 3) * 1024 + (n & 7);
#pragma unroll
    for (int mt = 0; mt < 8; mt++) {
#pragma unroll
        for (int reg = 0; reg < 4; reg++) {
            int o = mt * 16 + quad * 4 + reg;
            cb[base + o * 8] = f2b(acc[mt][reg]);
        }
    }

    // folded pack_adj: this wave packs 2 of the 8192 adjacency rows
    int wid = (blockIdx.y * gridDim.x + blockIdx.x) * 4 + wave;   // 0..4095
    const int* arow = adjg + (long)(wid * 2) * NN;
#pragma unroll
    for (int r = 0; r < 2; r++) {
#pragma unroll
        for (int it = 0; it < 16; it++) {
            unsigned long long m = __ballot(arow[it * 64 + lane] > 0);
            if (lane == 0) adjp[(long)(wid * 2 + r) * 16 + it] = m;
        }
        arow += NN;
    }
}

// ---------------- layer-1: split-K bf16 MFMA GEMM + LDS reduce + fused dots -
// block = 16 n x 128 o; 4 waves each own K/4 = 256; grid (64, B).
__global__ __launch_bounds__(256) void gemmT_sk(
    const ushort* __restrict__ AT,    // W_outTb [128][1024]
    const ushort* __restrict__ Bb,    // x_b [8192][1024]
    ushort* __restrict__ Cb,          // h2^T packed per b
    float* __restrict__ s1, float* __restrict__ s2,
    const float* __restrict__ a1g, const float* __restrict__ a2g)
{
    __shared__ float red[4 * 2304];   // [wave][o*18 + nl], 36,864 B
    int t = threadIdx.x;
    int wave = t >> 6, lane = t & 63;
    int quad = lane >> 4, l16 = lane & 15;
    int b = blockIdx.y;
    int n0 = blockIdx.x * 16;

    const ushort* brow = Bb + ((long)b * NN + n0 + l16) * HO;
    int kbase = wave * 256;

    floatx4 acc[8];
    floatx4 zero = {0.f, 0.f, 0.f, 0.f};
#pragma unroll
    for (int mt = 0; mt < 8; mt++) acc[mt] = zero;

    for (int k0 = 0; k0 < 256; k0 += 32) {
        int kb = kbase + k0 + quad * 8;
        short8 bfr = *(const short8*)(brow + kb);
#pragma unroll
        for (int mt = 0; mt < 8; mt++) {
            short8 af = *(const short8*)(AT + (long)(mt * 16 + l16) * HO + kb);
            acc[mt] = __builtin_amdgcn_mfma_f32_16x16x32_bf16(af, bfr, acc[mt], 0, 0, 0);
        }
    }

    // stash partials: o-stride 18 floats -> <=2-way bank aliasing (free)
#pragma unroll
    for (int mt = 0; mt < 8; mt++)
#pragma unroll
        for (int reg = 0; reg < 4; reg++)
            red[wave * 2304 + (mt * 16 + quad * 4 + reg) * 18 + l16] = acc[mt][reg];
    __syncthreads();

    // reduce: thread t -> nl = t&15, o in [ (t>>4)*8, +8 )
    int nl = t & 15, g = t >> 4, o0 = g * 8;
    float s[8];
#pragma unroll
    for (int k = 0; k < 8; k++) {
        int idx = (o0 + k) * 18 + nl;
        s[k] = red[idx] + red[2304 + idx] + red[4608 + idx] + red[6912 + idx];
    }

    // fused s1o/s2o partials over this thread's o-range
    float p1 = 0.f, p2 = 0.f;
#pragma unroll
    for (int k = 0; k < 8; k++) {
        p1 += s[k] * a1g[o0 + k];
        p2 += s[k] * a2g[o0 + k];
    }

    // packed h2^T store: (o, n=n0+nl) -> (n>>3)*1024 + o*8 + (n&7)
    ushort* cb = Cb + (long)b * OO * NN;
    int nglob = n0 + nl;
    int base = (nglob >> 3) * 1024 + (nglob & 7);
#pragma unroll
    for (int k = 0; k < 8; k++) cb[base + (o0 + k) * 8] = f2b(s[k]);

    // cross-group reduce of the dots
    __syncthreads();
    red[g * 16 + nl] = p1;
    red[256 + g * 16 + nl] = p2;
    __syncthreads();
    if (t < 16) {
        float q1 = 0.f, q2 = 0.f;
#pragma unroll
        for (int gg = 0; gg < 16; gg++) {
            q1 += red[gg * 16 + t];
            q2 += red[256 + gg * 16 + t];
        }
        s1[(long)b * NN + n0 + t] = q1;
        s2[(long)b * NN + n0 + t] = q2;
    }
}

// ---------------- single-pass masked-softmax attention + MFMA PV ------------
// JS=2 (layer 0): 4 waves = 2 i-groups(32 i) x 2 j-halves(512 j); LDS reduce.
// JS=4 (layer 1): 4 waves share one 16-i tile, 256 j each; LDS reduce.
// dyn LDS: s2s[1024] | red[8448] (stride 132) | Lred[64]
template <int JS>
__global__ __launch_bounds__(256) void attn_mfma(
    const float* __restrict__ s1g, const float* __restrict__ s2g,
    const ushort* __restrict__ hTp, const uint* __restrict__ adjp,
    float* __restrict__ outf, ushort* __restrict__ outb,
    int Hh, int outStride, int doElu, int writeBf)
{
    extern __shared__ float smem_f[];
    float* s2s = smem_f;
    float* red = smem_f + NN;
    float* Lred = red + 8448;

    int t = threadIdx.x;
    int wave = t >> 6, lane = t & 63;
    int quad = lane >> 4, l16 = lane & 15;
    int bh = blockIdx.y;
    int hh = bh % Hh, b = bh / Hh;

    const float* s2r = s2g + (long)bh * NN;
    for (int j = t; j < NN; j += 256) s2s[j] = s2r[j];
    __syncthreads();

    const ushort* hT = hTp + (long)bh * OO * NN;
    floatx4 zero = {0.f, 0.f, 0.f, 0.f};

    if (JS == 2) {
        int ig = wave >> 1, jh = wave & 1;
        int i0 = blockIdx.x * 64 + ig * 32;
        int j_lo = jh * (NN / 2), j_hi = j_lo + NN / 2;

        float s1a = s1g[(long)bh * NN + i0 + l16];
        float s1b = s1g[(long)bh * NN + i0 + 16 + l16];
        const uint* abA = adjp + ((long)b * NN + i0 + l16) * 32;
        const uint* abB = abA + 16 * 32;

        floatx4 acc0[8], acc1[8];
#pragma unroll
        for (int ot = 0; ot < 8; ot++) { acc0[ot] = zero; acc1[ot] = zero; }
        float Lp0 = 0.f, Lp1 = 0.f;

        for (int j0 = j_lo; j0 < j_hi; j0 += 32) {
            const ushort* hp = hT + ((j0 >> 3) + quad) * 1024 + l16 * 8;
            short8 bf[8];
#pragma unroll
            for (int ot = 0; ot < 8; ot++)
                bf[ot] = *(const short8*)(hp + ot * 128);
            uint mbA = (abA[j0 >> 5] >> (quad * 8)) & 0xffu;
            uint mbB = (abB[j0 >> 5] >> (quad * 8)) & 0xffu;
            int kb = j0 + quad * 8;
            float4 sA4 = *(const float4*)(s2s + kb);
            float4 sB4 = *(const float4*)(s2s + kb + 4);
            float se[8] = {sA4.x, sA4.y, sA4.z, sA4.w, sB4.x, sB4.y, sB4.z, sB4.w};
            short8 afA, afB;
#pragma unroll
            for (int e = 0; e < 8; e++) {
                float ea = s1a + se[e]; ea = fmaxf(ea, 0.2f * ea);
                float eb = s1b + se[e]; eb = fmaxf(eb, 0.2f * eb);
                union { float f; uint u; } wa, wb;
                wa.f = ((mbA >> e) & 1u) ? __expf(ea) : 0.f;
                wb.f = ((mbB >> e) & 1u) ? __expf(eb) : 0.f;
                wa.u &= 0xffff0000u; wb.u &= 0xffff0000u;   // truncate to bf16
                afA[e] = (short)(wa.u >> 16);
                afB[e] = (short)(wb.u >> 16);
                Lp0 += wa.f; Lp1 += wb.f;
            }
#pragma unroll
            for (int ot = 0; ot < 8; ot++) {
                acc0[ot] = __builtin_amdgcn_mfma_f32_16x16x32_bf16(afA, bf[ot], acc0[ot], 0, 0, 0);
                acc1[ot] = __builtin_amdgcn_mfma_f32_16x16x32_bf16(afB, bf[ot], acc1[ot], 0, 0, 0);
            }
        }

        Lp0 += __shfl_xor(Lp0, 16); Lp0 += __shfl_xor(Lp0, 32);
        Lp1 += __shfl_xor(Lp1, 16); Lp1 += __shfl_xor(Lp1, 32);

        if (jh == 1) {
#pragma unroll
            for (int ot = 0; ot < 8; ot++)
#pragma unroll
                for (int reg = 0; reg < 4; reg++) {
                    red[(ig * 32 + quad * 4 + reg) * 132 + ot * 16 + l16] = acc0[ot][reg];
                    red[(ig * 32 + 16 + quad * 4 + reg) * 132 + ot * 16 + l16] = acc1[ot][reg];
                }
            if (lane < 16) {
                Lred[(ig * 2 + 0) * 16 + l16] = Lp0;
                Lred[(ig * 2 + 1) * 16 + l16] = Lp1;
            }
        }
        __syncthreads();
        if (jh == 0) {
            float r0 = 1.0f / (Lp0 + Lred[(ig * 2 + 0) * 16 + l16]);
            float r1 = 1.0f / (Lp1 + Lred[(ig * 2 + 1) * 16 + l16]);
#pragma unroll
            for (int tile = 0; tile < 2; tile++) {
                float rv = tile ? r1 : r0;
                floatx4* ac = tile ? acc1 : acc0;
#pragma unroll
                for (int reg = 0; reg < 4; reg++) {
                    float linv = __shfl(rv, quad * 4 + reg);
                    int rloc = ig * 32 + tile * 16 + quad * 4 + reg;
                    int row = blockIdx.x * 64 + rloc;
                    if (writeBf) {
                        ushort* orow = outb + (long)b * NN * outStride + hh * OO +
                                       (long)row * outStride + l16;
#pragma unroll
                        for (int ot = 0; ot < 8; ot++) {
                            float v = (ac[ot][reg] + red[rloc * 132 + ot * 16 + l16]) * linv;
                            if (doElu) v = (v > 0.f) ? v : (__expf(v) - 1.0f);
                            orow[ot * 16] = f2b(v);
                        }
                    } else {
                        float* orow = outf + (long)b * NN * outStride + hh * OO +
                                      (long)row * outStride + l16;
#pragma unroll
                        for (int ot = 0; ot < 8; ot++) {
                            float v = (ac[ot][reg] + red[rloc * 132 + ot * 16 + l16]) * linv;
                            if (doElu) v = (v > 0.f) ? v : (__expf(v) - 1.0f);
                            orow[ot * 16] = v;
                        }
                    }
                }
            }
        }
    } else {   // JS == 4
        int i0 = blockIdx.x * 16;
        int j_lo = wave * (NN / 4), j_hi = j_lo + NN / 4;

        float s1a = s1g[(long)bh * NN + i0 + l16];
        const uint* abA = adjp + ((long)b * NN + i0 + l16) * 32;

        floatx4 acc[8];
#pragma unroll
        for (int ot = 0; ot < 8; ot++) acc[ot] = zero;
        float Lp = 0.f;

        for (int j0 = j_lo; j0 < j_hi; j0 += 32) {
            const ushort* hp = hT + ((j0 >> 3) + quad) * 1024 + l16 * 8;
            short8 bf[8];
#pragma unroll
            for (int ot = 0; ot < 8; ot++)
                bf[ot] = *(const short8*)(hp + ot * 128);
            uint mbA = (abA[j0 >> 5] >> (quad * 8)) & 0xffu;
            int kb = j0 + quad * 8;
            float4 sA4 = *(const float4*)(s2s + kb);
            float4 sB4 = *(const float4*)(s2s + kb + 4);
            float se[8] = {sA4.x, sA4.y, sA4.z, sA4.w, sB4.x, sB4.y, sB4.z, sB4.w};
            short8 afA;
#pragma unroll
            for (int e = 0; e < 8; e++) {
                float ea = s1a + se[e]; ea = fmaxf(ea, 0.2f * ea);
                union { float f; uint u; } wa;
                wa.f = ((mbA >> e) & 1u) ? __expf(ea) : 0.f;
                wa.u &= 0xffff0000u;
                afA[e] = (short)(wa.u >> 16);
                Lp += wa.f;
            }
#pragma unroll
            for (int ot = 0; ot < 8; ot++)
                acc[ot] = __builtin_amdgcn_mfma_f32_16x16x32_bf16(afA, bf[ot], acc[ot], 0, 0, 0);
        }

        Lp += __shfl_xor(Lp, 16); Lp += __shfl_xor(Lp, 32);
#pragma unroll
        for (int ot = 0; ot < 8; ot++)
#pragma unroll
            for (int reg = 0; reg < 4; reg++)
                red[(wave * 16 + quad * 4 + reg) * 132 + ot * 16 + l16] = acc[ot][reg];
        if (lane < 16) Lred[wave * 16 + l16] = Lp;
        __syncthreads();
        int row = t >> 4, c0 = (t & 15) * 8;
        float L = Lred[row] + Lred[16 + row] + Lred[32 + row] + Lred[48 + row];
        float rinv = 1.0f / L;
        int grow = i0 + row;
        float vv[8];
#pragma unroll
        for (int k = 0; k < 8; k++) {
            float s = red[row * 132 + c0 + k] + red[(16 + row) * 132 + c0 + k] +
                      red[(32 + row) * 132 + c0 + k] + red[(48 + row) * 132 + c0 + k];
            float v = s * rinv;
            if (doElu) v = (v > 0.f) ? v : (__expf(v) - 1.0f);
            vv[k] = v;
        }
        if (writeBf) {
            ushort* orow = outb + (long)b * NN * outStride + hh * OO +
                           (long)grow * outStride + c0;
#pragma unroll
            for (int k = 0; k < 8; k++) orow[k] = f2b(vv[k]);
        } else {
            float* orow = outf + (long)b * NN * outStride + hh * OO +
                          (long)grow * outStride + c0;
            *(float4*)orow = make_float4(vv[0], vv[1], vv[2], vv[3]);
            *(float4*)(orow + 4) = make_float4(vv[4], vv[5], vv[6], vv[7]);
        }
    }
}

// ---------------- final: y = x@lin_w.T+lin_b+out2; out = relu(y@ln_w.T+ln_b)
__global__ __launch_bounds__(256) void final_mfma(
    const ushort* __restrict__ xb, const float* __restrict__ out2,
    const ushort* __restrict__ lwb, const float* __restrict__ lin_b,
    const ushort* __restrict__ nwb, const float* __restrict__ ln_b,
    float* __restrict__ out)
{
    __shared__ ushort ys[32][136];
    int t = threadIdx.x;
    int wave = t >> 6, lane = t & 63;
    int quad = lane >> 4, l16 = lane & 15;
    long row0 = (long)blockIdx.x * 32;
    int n0 = wave * 32;

    floatx4 zero = {0.f, 0.f, 0.f, 0.f};
    floatx4 acc[2][2];
#pragma unroll
    for (int mt = 0; mt < 2; mt++)
#pragma unroll
        for (int nt = 0; nt < 2; nt++) acc[mt][nt] = zero;

    for (int k0 = 0; k0 < HO; k0 += 32) {
        int kb = k0 + quad * 8;
        short8 a0 = *(const short8*)(xb + (row0 + l16) * HO + kb);
        short8 a1 = *(const short8*)(xb + (row0 + 16 + l16) * HO + kb);
        short8 b0 = *(const short8*)(lwb + (long)(n0 + l16) * HO + kb);
        short8 b1 = *(const short8*)(lwb + (long)(n0 + 16 + l16) * HO + kb);
        acc[0][0] = __builtin_amdgcn_mfma_f32_16x16x32_bf16(a0, b0, acc[0][0], 0, 0, 0);
        acc[0][1] = __builtin_amdgcn_mfma_f32_16x16x32_bf16(a0, b1, acc[0][1], 0, 0, 0);
        acc[1][0] = __builtin_amdgcn_mfma_f32_16x16x32_bf16(a1, b0, acc[1][0], 0, 0, 0);
        acc[1][1] = __builtin_amdgcn_mfma_f32_16x16x32_bf16(a1, b1, acc[1][1], 0, 0, 0);
    }

#pragma unroll
    for (int nt = 0; nt < 2; nt++) {
        int col = n0 + nt * 16 + l16;
        float lb = lin_b[col];
#pragma unroll
        for (int mt = 0; mt < 2; mt++) {
#pragma unroll
            for (int reg = 0; reg < 4; reg++) {
                int row = mt * 16 + quad * 4 + reg;
                float v = acc[mt][nt][reg] + lb + out2[(row0 + row) * OO + col];
                ys[row][col] = f2b(v);
            }
        }
    }
    __syncthreads();

    floatx4 acc2[2][2];
#pragma unroll
    for (int mt = 0; mt < 2; mt++)
#pragma unroll
        for (int nt = 0; nt < 2; nt++) acc2[mt][nt] = zero;

#pragma unroll
    for (int k0 = 0; k0 < OO; k0 += 32) {
        int kb = k0 + quad * 8;
        short8 a0 = *(const short8*)&ys[l16][kb];
        short8 a1 = *(const short8*)&ys[16 + l16][kb];
        short8 b0 = *(const short8*)(nwb + (long)(n0 + l16) * OO + kb);
        short8 b1 = *(const short8*)(nwb + (long)(n0 + 16 + l16) * OO + kb);
        acc2[0][0] = __builtin_amdgcn_mfma_f32_16x16x32_bf16(a0, b0, acc2[0][0], 0, 0, 0);
        acc2[0][1] = __builtin_amdgcn_mfma_f32_16x16x32_bf16(a0, b1, acc2[0][1], 0, 0, 0);
        acc2[1][0] = __builtin_amdgcn_mfma_f32_16x16x32_bf16(a1, b0, acc2[1][0], 0, 0, 0);
        acc2[1][1] = __builtin_amdgcn_mfma_f32_16x16x32_bf16(a1, b1, acc2[1][1], 0, 0, 0);
    }

#pragma unroll
    for (int nt = 0; nt < 2; nt++) {
        int col = n0 + nt * 16 + l16;
        float nb = ln_b[col];
#pragma unroll
        for (int mt = 0; mt < 2; mt++) {
#pragma unroll
            for (int reg = 0; reg < 4; reg++) {
                int row = mt * 16 + quad * 4 + reg;
                out[(row0 + row) * OO + col] = fmaxf(acc2[mt][nt][reg] + nb, 0.f);
            }
        }
    }
}

extern "C" void kernel_launch(void* const* d_in, const int* in_sizes, int n_in,
                              void* d_out, int out_size, void* d_ws, size_t ws_size,
                              hipStream_t stream)
{
    const float* inputs = (const float*)d_in[0];
    const int*   adj    = (const int*)d_in[1];
    const float* W_att  = (const float*)d_in[3];
    const float* a_src  = (const float*)d_in[4];
    const float* a_dst  = (const float*)d_in[5];
    const float* W_out  = (const float*)d_in[6];
    const float* ao_src = (const float*)d_in[7];
    const float* ao_dst = (const float*)d_in[8];
    const float* lin_w  = (const float*)d_in[9];
    const float* lin_b  = (const float*)d_in[10];
    const float* ln_w   = (const float*)d_in[11];
    const float* ln_b   = (const float*)d_in[12];
    float* out = (float*)d_out;

    float* ws   = (float*)d_ws;
    float* out2 = ws;
    float* s1   = ws + 1048576;
    float* s2   = ws + 1114112;
    float* s1o  = ws + 1179648;
    float* s2o  = ws + 1187840;
    ushort* ub      = (ushort*)(ws + 1196032);
    ushort* x_b     = ub;
    ushort* h_catTb = ub + 8388608;
    ushort* h2Tb    = ub + 16777216;
    ushort* W_attTb = ub + 17825792;
    ushort* W_outTb = ub + 18087936;
    ushort* lin_wb  = ub + 18219008;
    ushort* ln_wb   = ub + 18350080;
    unsigned long long* adjp = (unsigned long long*)(ub + 18366464);

    const int SH = (NN + 8448 + 64) * 4;   // 38,144 B dyn LDS

    // 0. weight conversions (merged cvt)
    transpose_cvt<<<dim3(4, 2, 8), 256, 0, stream>>>(W_att, W_attTb, FF, OO);
    transpose_cvt<<<dim3(16, 2, 1), 256, 0, stream>>>(W_out, W_outTb, HO, OO);
    cvt_bf16_2<<<72, 256, 0, stream>>>(lin_w, lin_wb, 131072L, ln_w, ln_wb);
    // 1. h^T (packed) = (inputs @ W_att)^T per (b,h), bf16; fused s1/s2;
    //    folded adj bit-packing (2 rows/wave)
    gemmT<<<dim3(16, 64), 256, 0, stream>>>(
        W_attTb, inputs, h_catTb, s1, s2, a_src, a_dst, FF, HH, adj, adjp);
    // 2. layer-0 attention -> x = elu(att@h) bf16
    attn_mfma<2><<<dim3(16, 64), 256, SH, stream>>>(
        s1, s2, h_catTb, (const uint*)adjp, (float*)nullptr, x_b, HH, HO, 1, 1);
    // 3. h2^T (packed) = (x @ W_out)^T per b, split-K x4; fused s1o/s2o
    gemmT_sk<<<dim3(64, 8), 256, 0, stream>>>(
        W_outTb, x_b, h2Tb, s1o, s2o, ao_src, ao_dst);
    // 4. layer-1 attention -> out2 fp32 (no elu), j-split x4
    attn_mfma<4><<<dim3(64, 8), 256, SH, stream>>>(
        s1o, s2o, h2Tb, (const uint*)adjp, out2, (ushort*)nullptr, 1, OO, 0, 0);
    // 5. out = relu((x@lin_w.T + lin_b + out2) @ ln_w.T + ln_b)
    final_mfma<<<256, 256, 0, stream>>>(
        x_b, out2, lin_wb, lin_b, ln_wb, ln_b, out);
}

// Round 7
// 248.672 us; speedup vs baseline: 1.5490x; 1.0489x over previous
//
#include <hip/hip_runtime.h>

// GAT forward, MI355X. Round 6: pack_adj un-folded (R5 fold regressed gemmT0
// 45->87us: BW-stream task in a latency-bound kernel with 1/4 the waves);
// attn_mfma gets cross-iteration register double-buffering of B-fragments.
// B=8, N=1024, F=256, O=128, H=8, HO=1024, BH=64.
//
// h^T packed layout per (b,h): elem (j,o) at (j>>3)*1024 + o*8 + (j&7).
//
// ws floats:
//   out2 [8192,128] @ 0        (1,048,576)
//   s1 @ 1048576  s2 @ 1114112 (65,536 each)
//   s1o @ 1179648 s2o @ 1187840 (8,192 each)
// ushort region @ float offset 1196032:
//   x_b     [8,1024,1024] @ 0         h_catTb @ 8388608   h2Tb @ 16777216
//   W_attTb @ 17825792    W_outTb @ 18087936
//   lin_wb  @ 18219008    ln_wb   @ 18350080
//   adjp (ull[8192*16]) @ ushort 18366464  (1 MB)

#define NN 1024
#define FF 256
#define OO 128
#define HH 8
#define HO 1024

typedef __attribute__((ext_vector_type(8))) short short8;
typedef __attribute__((ext_vector_type(4))) float floatx4;

__device__ __forceinline__ ushort f2b(float f) {
    union { float f; unsigned u; } v; v.f = f;
    unsigned r = v.u + 0x7FFFu + ((v.u >> 16) & 1u);   // RNE
    return (ushort)(r >> 16);
}

// ---------------- adj int32 -> bitmask (standalone; 8192 waves, BW-bound) ---
__global__ __launch_bounds__(256) void pack_adj(
    const int* __restrict__ adj, unsigned long long* __restrict__ adjp)
{
    int w = blockIdx.x * 4 + (threadIdx.x >> 6);   // row 0..8191 (= b*N+i)
    int lane = threadIdx.x & 63;
    const int* row = adj + (long)w * NN;
#pragma unroll
    for (int it = 0; it < 16; it++) {
        unsigned long long m = __ballot(row[it * 64 + lane] > 0);
        if (lane == 0) adjp[(long)w * 16 + it] = m;
    }
}

// ---------------- transpose + bf16 cvt: dst[z][c][r] = src[z][r][c] ----------
__global__ __launch_bounds__(256) void transpose_cvt(
    const float* __restrict__ src, ushort* __restrict__ dst, int R, int C)
{
    __shared__ float tile[64][65];
    int r0 = blockIdx.x * 64, c0 = blockIdx.y * 64;
    src += (long)blockIdx.z * R * C;
    dst += (long)blockIdx.z * R * C;
    int t = threadIdx.x;
    int lr = t >> 4, lc = (t & 15) * 4;
#pragma unroll
    for (int p = 0; p < 4; p++) {
        float4 v = *(const float4*)(src + (long)(r0 + p * 16 + lr) * C + c0 + lc);
        tile[p * 16 + lr][lc] = v.x; tile[p * 16 + lr][lc + 1] = v.y;
        tile[p * 16 + lr][lc + 2] = v.z; tile[p * 16 + lr][lc + 3] = v.w;
    }
    __syncthreads();
    int c = t >> 2, rq = (t & 3) * 16;
    union { ushort s[16]; uint4 q[2]; } u;
#pragma unroll
    for (int k = 0; k < 16; k++) u.s[k] = f2b(tile[rq + k][c]);
    uint4* dp = (uint4*)(dst + (long)(c0 + c) * R + r0 + rq);
    dp[0] = u.q[0]; dp[1] = u.q[1];
}

// ---------------- merged fp32->bf16 cvt for lin_w (131072) + ln_w (16384) ---
__global__ __launch_bounds__(256) void cvt_bf16_2(
    const float* __restrict__ s0, ushort* __restrict__ d0, long n0,
    const float* __restrict__ s1, ushort* __restrict__ d1)
{
    long i = ((long)blockIdx.x * 256 + threadIdx.x) * 8;
    const float* src; ushort* dst; long off;
    if (i < n0) { src = s0; dst = d0; off = i; }
    else        { src = s1; dst = d1; off = i - n0; }
    float4 v0 = *(const float4*)(src + off);
    float4 v1 = *(const float4*)(src + off + 4);
    union { ushort s[8]; uint4 q; } u;
    u.s[0] = f2b(v0.x); u.s[1] = f2b(v0.y); u.s[2] = f2b(v0.z); u.s[3] = f2b(v0.w);
    u.s[4] = f2b(v1.x); u.s[5] = f2b(v1.y); u.s[6] = f2b(v1.z); u.s[7] = f2b(v1.w);
    *(uint4*)(dst + off) = u.q;
}

// ---------------- layer-0: bf16 MFMA "NT" GEMM, packed-h^T out, fused dots --
__global__ __launch_bounds__(256) void gemmT(
    const ushort* __restrict__ AT, const float* __restrict__ Bf,
    ushort* __restrict__ Cb, float* __restrict__ s1, float* __restrict__ s2,
    const float* __restrict__ a1g, const float* __restrict__ a2g,
    int K, int Hh)
{
    int t = threadIdx.x;
    int wave = t >> 6, lane = t & 63;
    int quad = lane >> 4, l16 = lane & 15;
    int bh = blockIdx.y;
    int hh = bh % Hh, b = bh / Hh;
    int n0w = blockIdx.x * 64 + wave * 16;

    const ushort* A = AT + (long)hh * OO * K;
    const float* browf = Bf + ((long)b * NN + n0w + l16) * K;

    floatx4 acc[8];
    floatx4 zero = {0.f, 0.f, 0.f, 0.f};
#pragma unroll
    for (int mt = 0; mt < 8; mt++) acc[mt] = zero;

    for (int k0 = 0; k0 < K; k0 += 32) {
        int kb = k0 + quad * 8;
        float4 b0 = *(const float4*)(browf + kb);
        float4 b1 = *(const float4*)(browf + kb + 4);
        short8 bfr;
        bfr[0] = (short)f2b(b0.x); bfr[1] = (short)f2b(b0.y);
        bfr[2] = (short)f2b(b0.z); bfr[3] = (short)f2b(b0.w);
        bfr[4] = (short)f2b(b1.x); bfr[5] = (short)f2b(b1.y);
        bfr[6] = (short)f2b(b1.z); bfr[7] = (short)f2b(b1.w);
#pragma unroll
        for (int mt = 0; mt < 8; mt++) {
            short8 af = *(const short8*)(A + (long)(mt * 16 + l16) * K + kb);
            acc[mt] = __builtin_amdgcn_mfma_f32_16x16x32_bf16(af, bfr, acc[mt], 0, 0, 0);
        }
    }

    const float* a1 = a1g + hh * OO;
    const float* a2 = a2g + hh * OO;
    float sp1 = 0.f, sp2 = 0.f;
#pragma unroll
    for (int mt = 0; mt < 8; mt++) {
        float4 v1 = *(const float4*)(a1 + mt * 16 + quad * 4);
        float4 v2 = *(const float4*)(a2 + mt * 16 + quad * 4);
        sp1 += acc[mt][0] * v1.x + acc[mt][1] * v1.y + acc[mt][2] * v1.z + acc[mt][3] * v1.w;
        sp2 += acc[mt][0] * v2.x + acc[mt][1] * v2.y + acc[mt][2] * v2.z + acc[mt][3] * v2.w;
    }
    sp1 += __shfl_xor(sp1, 16); sp1 += __shfl_xor(sp1, 32);
    sp2 += __shfl_xor(sp2, 16); sp2 += __shfl_xor(sp2, 32);
    if (lane < 16) {
        s1[(long)bh * NN + n0w + l16] = sp1;
        s2[(long)bh * NN + n0w + l16] = sp2;
    }

    // store h^T bf16, fragment-packed: (o,n) -> (n>>3)*1024 + o*8 + (n&7)
    ushort* cb = Cb + (long)bh * OO * NN;
    int n = n0w + l16;
    int base = (n >> 3) * 1024 + (n & 7);
#pragma unroll
    for (int mt = 0; mt < 8; mt++) {
#pragma unroll
        for (int reg = 0; reg < 4; reg++) {
            int o = mt * 16 + quad * 4 + reg;
            cb[base + o * 8] = f2b(acc[mt][reg]);
        }
    }
}

// ---------------- layer-1: split-K bf16 MFMA GEMM + LDS reduce + fused dots -
__global__ __launch_bounds__(256) void gemmT_sk(
    const ushort* __restrict__ AT,    // W_outTb [128][1024]
    const ushort* __restrict__ Bb,    // x_b [8192][1024]
    ushort* __restrict__ Cb,          // h2^T packed per b
    float* __restrict__ s1, float* __restrict__ s2,
    const float* __restrict__ a1g, const float* __restrict__ a2g)
{
    __shared__ float red[4 * 2304];   // [wave][o*18 + nl], 36,864 B
    int t = threadIdx.x;
    int wave = t >> 6, lane = t & 63;
    int quad = lane >> 4, l16 = lane & 15;
    int b = blockIdx.y;
    int n0 = blockIdx.x * 16;

    const ushort* brow = Bb + ((long)b * NN + n0 + l16) * HO;
    int kbase = wave * 256;

    floatx4 acc[8];
    floatx4 zero = {0.f, 0.f, 0.f, 0.f};
#pragma unroll
    for (int mt = 0; mt < 8; mt++) acc[mt] = zero;

    for (int k0 = 0; k0 < 256; k0 += 32) {
        int kb = kbase + k0 + quad * 8;
        short8 bfr = *(const short8*)(brow + kb);
#pragma unroll
        for (int mt = 0; mt < 8; mt++) {
            short8 af = *(const short8*)(AT + (long)(mt * 16 + l16) * HO + kb);
            acc[mt] = __builtin_amdgcn_mfma_f32_16x16x32_bf16(af, bfr, acc[mt], 0, 0, 0);
        }
    }

#pragma unroll
    for (int mt = 0; mt < 8; mt++)
#pragma unroll
        for (int reg = 0; reg < 4; reg++)
            red[wave * 2304 + (mt * 16 + quad * 4 + reg) * 18 + l16] = acc[mt][reg];
    __syncthreads();

    int nl = t & 15, g = t >> 4, o0 = g * 8;
    float s[8];
#pragma unroll
    for (int k = 0; k < 8; k++) {
        int idx = (o0 + k) * 18 + nl;
        s[k] = red[idx] + red[2304 + idx] + red[4608 + idx] + red[6912 + idx];
    }

    float p1 = 0.f, p2 = 0.f;
#pragma unroll
    for (int k = 0; k < 8; k++) {
        p1 += s[k] * a1g[o0 + k];
        p2 += s[k] * a2g[o0 + k];
    }

    ushort* cb = Cb + (long)b * OO * NN;
    int nglob = n0 + nl;
    int base = (nglob >> 3) * 1024 + (nglob & 7);
#pragma unroll
    for (int k = 0; k < 8; k++) cb[base + (o0 + k) * 8] = f2b(s[k]);

    __syncthreads();
    red[g * 16 + nl] = p1;
    red[256 + g * 16 + nl] = p2;
    __syncthreads();
    if (t < 16) {
        float q1 = 0.f, q2 = 0.f;
#pragma unroll
        for (int gg = 0; gg < 16; gg++) {
            q1 += red[gg * 16 + t];
            q2 += red[256 + gg * 16 + t];
        }
        s1[(long)b * NN + n0 + t] = q1;
        s2[(long)b * NN + n0 + t] = q2;
    }
}

// ---------------- single-pass masked-softmax attention + MFMA PV ------------
// JS=2 (layer 0): 4 waves = 2 i-groups(32 i) x 2 j-halves(512 j); LDS reduce.
// JS=4 (layer 1): 4 waves share one 16-i tile, 256 j each; LDS reduce.
// B-fragments register-double-buffered: iter k+1 loads issued before iter k's
// MFMAs so L2 latency hides under VALU e^ + previous MFMA block.
// dyn LDS: s2s[1024] | red[8448] (stride 132) | Lred[64]
template <int JS>
__global__ __launch_bounds__(256) void attn_mfma(
    const float* __restrict__ s1g, const float* __restrict__ s2g,
    const ushort* __restrict__ hTp, const uint* __restrict__ adjp,
    float* __restrict__ outf, ushort* __restrict__ outb,
    int Hh, int outStride, int doElu, int writeBf)
{
    extern __shared__ float smem_f[];
    float* s2s = smem_f;
    float* red = smem_f + NN;
    float* Lred = red + 8448;

    int t = threadIdx.x;
    int wave = t >> 6, lane = t & 63;
    int quad = lane >> 4, l16 = lane & 15;
    int bh = blockIdx.y;
    int hh = bh % Hh, b = bh / Hh;

    const float* s2r = s2g + (long)bh * NN;
    for (int j = t; j < NN; j += 256) s2s[j] = s2r[j];
    __syncthreads();

    const ushort* hT = hTp + (long)bh * OO * NN;
    floatx4 zero = {0.f, 0.f, 0.f, 0.f};

    if (JS == 2) {
        int ig = wave >> 1, jh = wave & 1;
        int i0 = blockIdx.x * 64 + ig * 32;
        int j_lo = jh * (NN / 2), j_hi = j_lo + NN / 2;

        float s1a = s1g[(long)bh * NN + i0 + l16];
        float s1b = s1g[(long)bh * NN + i0 + 16 + l16];
        const uint* abA = adjp + ((long)b * NN + i0 + l16) * 32;
        const uint* abB = abA + 16 * 32;

        floatx4 acc0[8], acc1[8];
#pragma unroll
        for (int ot = 0; ot < 8; ot++) { acc0[ot] = zero; acc1[ot] = zero; }
        float Lp0 = 0.f, Lp1 = 0.f;

        const ushort* hp0 = hT + ((j_lo >> 3) + quad) * 1024 + l16 * 8;
        short8 bfn[8];
#pragma unroll
        for (int ot = 0; ot < 8; ot++) bfn[ot] = *(const short8*)(hp0 + ot * 128);

        for (int j0 = j_lo; j0 < j_hi; j0 += 32) {
            short8 bf[8];
#pragma unroll
            for (int ot = 0; ot < 8; ot++) bf[ot] = bfn[ot];
            if (j0 + 32 < j_hi) {
                const ushort* hp = hT + (((j0 + 32) >> 3) + quad) * 1024 + l16 * 8;
#pragma unroll
                for (int ot = 0; ot < 8; ot++) bfn[ot] = *(const short8*)(hp + ot * 128);
            }
            uint mbA = (abA[j0 >> 5] >> (quad * 8)) & 0xffu;
            uint mbB = (abB[j0 >> 5] >> (quad * 8)) & 0xffu;
            int kb = j0 + quad * 8;
            float4 sA4 = *(const float4*)(s2s + kb);
            float4 sB4 = *(const float4*)(s2s + kb + 4);
            float se[8] = {sA4.x, sA4.y, sA4.z, sA4.w, sB4.x, sB4.y, sB4.z, sB4.w};
            short8 afA, afB;
#pragma unroll
            for (int e = 0; e < 8; e++) {
                float ea = s1a + se[e]; ea = fmaxf(ea, 0.2f * ea);
                float eb = s1b + se[e]; eb = fmaxf(eb, 0.2f * eb);
                union { float f; uint u; } wa, wb;
                wa.f = ((mbA >> e) & 1u) ? __expf(ea) : 0.f;
                wb.f = ((mbB >> e) & 1u) ? __expf(eb) : 0.f;
                wa.u &= 0xffff0000u; wb.u &= 0xffff0000u;   // truncate to bf16
                afA[e] = (short)(wa.u >> 16);
                afB[e] = (short)(wb.u >> 16);
                Lp0 += wa.f; Lp1 += wb.f;
            }
#pragma unroll
            for (int ot = 0; ot < 8; ot++) {
                acc0[ot] = __builtin_amdgcn_mfma_f32_16x16x32_bf16(afA, bf[ot], acc0[ot], 0, 0, 0);
                acc1[ot] = __builtin_amdgcn_mfma_f32_16x16x32_bf16(afB, bf[ot], acc1[ot], 0, 0, 0);
            }
        }

        Lp0 += __shfl_xor(Lp0, 16); Lp0 += __shfl_xor(Lp0, 32);
        Lp1 += __shfl_xor(Lp1, 16); Lp1 += __shfl_xor(Lp1, 32);

        if (jh == 1) {
#pragma unroll
            for (int ot = 0; ot < 8; ot++)
#pragma unroll
                for (int reg = 0; reg < 4; reg++) {
                    red[(ig * 32 + quad * 4 + reg) * 132 + ot * 16 + l16] = acc0[ot][reg];
                    red[(ig * 32 + 16 + quad * 4 + reg) * 132 + ot * 16 + l16] = acc1[ot][reg];
                }
            if (lane < 16) {
                Lred[(ig * 2 + 0) * 16 + l16] = Lp0;
                Lred[(ig * 2 + 1) * 16 + l16] = Lp1;
            }
        }
        __syncthreads();
        if (jh == 0) {
            float r0 = 1.0f / (Lp0 + Lred[(ig * 2 + 0) * 16 + l16]);
            float r1 = 1.0f / (Lp1 + Lred[(ig * 2 + 1) * 16 + l16]);
#pragma unroll
            for (int tile = 0; tile < 2; tile++) {
                float rv = tile ? r1 : r0;
                floatx4* ac = tile ? acc1 : acc0;
#pragma unroll
                for (int reg = 0; reg < 4; reg++) {
                    float linv = __shfl(rv, quad * 4 + reg);
                    int rloc = ig * 32 + tile * 16 + quad * 4 + reg;
                    int row = blockIdx.x * 64 + rloc;
                    if (writeBf) {
                        ushort* orow = outb + (long)b * NN * outStride + hh * OO +
                                       (long)row * outStride + l16;
#pragma unroll
                        for (int ot = 0; ot < 8; ot++) {
                            float v = (ac[ot][reg] + red[rloc * 132 + ot * 16 + l16]) * linv;
                            if (doElu) v = (v > 0.f) ? v : (__expf(v) - 1.0f);
                            orow[ot * 16] = f2b(v);
                        }
                    } else {
                        float* orow = outf + (long)b * NN * outStride + hh * OO +
                                      (long)row * outStride + l16;
#pragma unroll
                        for (int ot = 0; ot < 8; ot++) {
                            float v = (ac[ot][reg] + red[rloc * 132 + ot * 16 + l16]) * linv;
                            if (doElu) v = (v > 0.f) ? v : (__expf(v) - 1.0f);
                            orow[ot * 16] = v;
                        }
                    }
                }
            }
        }
    } else {   // JS == 4
        int i0 = blockIdx.x * 16;
        int j_lo = wave * (NN / 4), j_hi = j_lo + NN / 4;

        float s1a = s1g[(long)bh * NN + i0 + l16];
        const uint* abA = adjp + ((long)b * NN + i0 + l16) * 32;

        floatx4 acc[8];
#pragma unroll
        for (int ot = 0; ot < 8; ot++) acc[ot] = zero;
        float Lp = 0.f;

        const ushort* hp0 = hT + ((j_lo >> 3) + quad) * 1024 + l16 * 8;
        short8 bfn[8];
#pragma unroll
        for (int ot = 0; ot < 8; ot++) bfn[ot] = *(const short8*)(hp0 + ot * 128);

        for (int j0 = j_lo; j0 < j_hi; j0 += 32) {
            short8 bf[8];
#pragma unroll
            for (int ot = 0; ot < 8; ot++) bf[ot] = bfn[ot];
            if (j0 + 32 < j_hi) {
                const ushort* hp = hT + (((j0 + 32) >> 3) + quad) * 1024 + l16 * 8;
#pragma unroll
                for (int ot = 0; ot < 8; ot++) bfn[ot] = *(const short8*)(hp + ot * 128);
            }
            uint mbA = (abA[j0 >> 5] >> (quad * 8)) & 0xffu;
            int kb = j0 + quad * 8;
            float4 sA4 = *(const float4*)(s2s + kb);
            float4 sB4 = *(const float4*)(s2s + kb + 4);
            float se[8] = {sA4.x, sA4.y, sA4.z, sA4.w, sB4.x, sB4.y, sB4.z, sB4.w};
            short8 afA;
#pragma unroll
            for (int e = 0; e < 8; e++) {
                float ea = s1a + se[e]; ea = fmaxf(ea, 0.2f * ea);
                union { float f; uint u; } wa;
                wa.f = ((mbA >> e) & 1u) ? __expf(ea) : 0.f;
                wa.u &= 0xffff0000u;
                afA[e] = (short)(wa.u >> 16);
                Lp += wa.f;
            }
#pragma unroll
            for (int ot = 0; ot < 8; ot++)
                acc[ot] = __builtin_amdgcn_mfma_f32_16x16x32_bf16(afA, bf[ot], acc[ot], 0, 0, 0);
        }

        Lp += __shfl_xor(Lp, 16); Lp += __shfl_xor(Lp, 32);
#pragma unroll
        for (int ot = 0; ot < 8; ot++)
#pragma unroll
            for (int reg = 0; reg < 4; reg++)
                red[(wave * 16 + quad * 4 + reg) * 132 + ot * 16 + l16] = acc[ot][reg];
        if (lane < 16) Lred[wave * 16 + l16] = Lp;
        __syncthreads();
        int row = t >> 4, c0 = (t & 15) * 8;
        float L = Lred[row] + Lred[16 + row] + Lred[32 + row] + Lred[48 + row];
        float rinv = 1.0f / L;
        int grow = i0 + row;
        float vv[8];
#pragma unroll
        for (int k = 0; k < 8; k++) {
            float s = red[row * 132 + c0 + k] + red[(16 + row) * 132 + c0 + k] +
                      red[(32 + row) * 132 + c0 + k] + red[(48 + row) * 132 + c0 + k];
            float v = s * rinv;
            if (doElu) v = (v > 0.f) ? v : (__expf(v) - 1.0f);
            vv[k] = v;
        }
        if (writeBf) {
            ushort* orow = outb + (long)b * NN * outStride + hh * OO +
                           (long)grow * outStride + c0;
#pragma unroll
            for (int k = 0; k < 8; k++) orow[k] = f2b(vv[k]);
        } else {
            float* orow = outf + (long)b * NN * outStride + hh * OO +
                          (long)grow * outStride + c0;
            *(float4*)orow = make_float4(vv[0], vv[1], vv[2], vv[3]);
            *(float4*)(orow + 4) = make_float4(vv[4], vv[5], vv[6], vv[7]);
        }
    }
}

// ---------------- final: y = x@lin_w.T+lin_b+out2; out = relu(y@ln_w.T+ln_b)
__global__ __launch_bounds__(256) void final_mfma(
    const ushort* __restrict__ xb, const float* __restrict__ out2,
    const ushort* __restrict__ lwb, const float* __restrict__ lin_b,
    const ushort* __restrict__ nwb, const float* __restrict__ ln_b,
    float* __restrict__ out)
{
    __shared__ ushort ys[32][136];
    int t = threadIdx.x;
    int wave = t >> 6, lane = t & 63;
    int quad = lane >> 4, l16 = lane & 15;
    long row0 = (long)blockIdx.x * 32;
    int n0 = wave * 32;

    floatx4 zero = {0.f, 0.f, 0.f, 0.f};
    floatx4 acc[2][2];
#pragma unroll
    for (int mt = 0; mt < 2; mt++)
#pragma unroll
        for (int nt = 0; nt < 2; nt++) acc[mt][nt] = zero;

    for (int k0 = 0; k0 < HO; k0 += 32) {
        int kb = k0 + quad * 8;
        short8 a0 = *(const short8*)(xb + (row0 + l16) * HO + kb);
        short8 a1 = *(const short8*)(xb + (row0 + 16 + l16) * HO + kb);
        short8 b0 = *(const short8*)(lwb + (long)(n0 + l16) * HO + kb);
        short8 b1 = *(const short8*)(lwb + (long)(n0 + 16 + l16) * HO + kb);
        acc[0][0] = __builtin_amdgcn_mfma_f32_16x16x32_bf16(a0, b0, acc[0][0], 0, 0, 0);
        acc[0][1] = __builtin_amdgcn_mfma_f32_16x16x32_bf16(a0, b1, acc[0][1], 0, 0, 0);
        acc[1][0] = __builtin_amdgcn_mfma_f32_16x16x32_bf16(a1, b0, acc[1][0], 0, 0, 0);
        acc[1][1] = __builtin_amdgcn_mfma_f32_16x16x32_bf16(a1, b1, acc[1][1], 0, 0, 0);
    }

#pragma unroll
    for (int nt = 0; nt < 2; nt++) {
        int col = n0 + nt * 16 + l16;
        float lb = lin_b[col];
#pragma unroll
        for (int mt = 0; mt < 2; mt++) {
#pragma unroll
            for (int reg = 0; reg < 4; reg++) {
                int row = mt * 16 + quad * 4 + reg;
                float v = acc[mt][nt][reg] + lb + out2[(row0 + row) * OO + col];
                ys[row][col] = f2b(v);
            }
        }
    }
    __syncthreads();

    floatx4 acc2[2][2];
#pragma unroll
    for (int mt = 0; mt < 2; mt++)
#pragma unroll
        for (int nt = 0; nt < 2; nt++) acc2[mt][nt] = zero;

#pragma unroll
    for (int k0 = 0; k0 < OO; k0 += 32) {
        int kb = k0 + quad * 8;
        short8 a0 = *(const short8*)&ys[l16][kb];
        short8 a1 = *(const short8*)&ys[16 + l16][kb];
        short8 b0 = *(const short8*)(nwb + (long)(n0 + l16) * OO + kb);
        short8 b1 = *(const short8*)(nwb + (long)(n0 + 16 + l16) * OO + kb);
        acc2[0][0] = __builtin_amdgcn_mfma_f32_16x16x32_bf16(a0, b0, acc2[0][0], 0, 0, 0);
        acc2[0][1] = __builtin_amdgcn_mfma_f32_16x16x32_bf16(a0, b1, acc2[0][1], 0, 0, 0);
        acc2[1][0] = __builtin_amdgcn_mfma_f32_16x16x32_bf16(a1, b0, acc2[1][0], 0, 0, 0);
        acc2[1][1] = __builtin_amdgcn_mfma_f32_16x16x32_bf16(a1, b1, acc2[1][1], 0, 0, 0);
    }

#pragma unroll
    for (int nt = 0; nt < 2; nt++) {
        int col = n0 + nt * 16 + l16;
        float nb = ln_b[col];
#pragma unroll
        for (int mt = 0; mt < 2; mt++) {
#pragma unroll
            for (int reg = 0; reg < 4; reg++) {
                int row = mt * 16 + quad * 4 + reg;
                out[(row0 + row) * OO + col] = fmaxf(acc2[mt][nt][reg] + nb, 0.f);
            }
        }
    }
}

extern "C" void kernel_launch(void* const* d_in, const int* in_sizes, int n_in,
                              void* d_out, int out_size, void* d_ws, size_t ws_size,
                              hipStream_t stream)
{
    const float* inputs = (const float*)d_in[0];
    const int*   adj    = (const int*)d_in[1];
    const float* W_att  = (const float*)d_in[3];
    const float* a_src  = (const float*)d_in[4];
    const float* a_dst  = (const float*)d_in[5];
    const float* W_out  = (const float*)d_in[6];
    const float* ao_src = (const float*)d_in[7];
    const float* ao_dst = (const float*)d_in[8];
    const float* lin_w  = (const float*)d_in[9];
    const float* lin_b  = (const float*)d_in[10];
    const float* ln_w   = (const float*)d_in[11];
    const float* ln_b   = (const float*)d_in[12];
    float* out = (float*)d_out;

    float* ws   = (float*)d_ws;
    float* out2 = ws;
    float* s1   = ws + 1048576;
    float* s2   = ws + 1114112;
    float* s1o  = ws + 1179648;
    float* s2o  = ws + 1187840;
    ushort* ub      = (ushort*)(ws + 1196032);
    ushort* x_b     = ub;
    ushort* h_catTb = ub + 8388608;
    ushort* h2Tb    = ub + 16777216;
    ushort* W_attTb = ub + 17825792;
    ushort* W_outTb = ub + 18087936;
    ushort* lin_wb  = ub + 18219008;
    ushort* ln_wb   = ub + 18350080;
    unsigned long long* adjp = (unsigned long long*)(ub + 18366464);

    const int SH = (NN + 8448 + 64) * 4;   // 38,144 B dyn LDS

    // 0. packing / conversions
    pack_adj<<<2048, 256, 0, stream>>>(adj, adjp);
    transpose_cvt<<<dim3(4, 2, 8), 256, 0, stream>>>(W_att, W_attTb, FF, OO);
    transpose_cvt<<<dim3(16, 2, 1), 256, 0, stream>>>(W_out, W_outTb, HO, OO);
    cvt_bf16_2<<<72, 256, 0, stream>>>(lin_w, lin_wb, 131072L, ln_w, ln_wb);
    // 1. h^T (packed) = (inputs @ W_att)^T per (b,h), bf16; fused s1/s2
    gemmT<<<dim3(16, 64), 256, 0, stream>>>(
        W_attTb, inputs, h_catTb, s1, s2, a_src, a_dst, FF, HH);
    // 2. layer-0 attention -> x = elu(att@h) bf16
    attn_mfma<2><<<dim3(16, 64), 256, SH, stream>>>(
        s1, s2, h_catTb, (const uint*)adjp, (float*)nullptr, x_b, HH, HO, 1, 1);
    // 3. h2^T (packed) = (x @ W_out)^T per b, split-K x4; fused s1o/s2o
    gemmT_sk<<<dim3(64, 8), 256, 0, stream>>>(
        W_outTb, x_b, h2Tb, s1o, s2o, ao_src, ao_dst);
    // 4. layer-1 attention -> out2 fp32 (no elu), j-split x4
    attn_mfma<4><<<dim3(64, 8), 256, SH, stream>>>(
        s1o, s2o, h2Tb, (const uint*)adjp, out2, (ushort*)nullptr, 1, OO, 0, 0);
    // 5. out = relu((x@lin_w.T + lin_b + out2) @ ln_w.T + ln_b)
    final_mfma<<<256, 256, 0, stream>>>(
        x_b, out2, lin_wb, lin_b, ln_wb, ln_b, out);
}